// Round 1
// baseline (61173.151 us; speedup 1.0000x reference)
//
#include <hip/hip_runtime.h>

typedef unsigned short u16;
typedef __bf16 bf16x8 __attribute__((ext_vector_type(8)));
typedef float f32x4 __attribute__((ext_vector_type(4)));

__device__ __forceinline__ u16 f2b(float f) {
  unsigned u = __builtin_bit_cast(unsigned, f);
  u = (u + 0x7FFFu + ((u >> 16) & 1u)) >> 16;
  return (u16)u;
}
__device__ __forceinline__ float b2f(u16 h) {
  return __builtin_bit_cast(float, ((unsigned)h) << 16);
}
__device__ __forceinline__ float sigmoidf_(float x) { return 1.0f / (1.0f + expf(-x)); }

// ---------------- generic bf16 MFMA GEMM: C[M,N] = A[M,K] @ B[N,K]^T (+C) (+bias) ----------------
// EPI: 0 none, 1 relu, 2 tanh. OUTBF: bf16 output. ACC: accumulate into fp32 Cout.
// All of M%64==0, N%64==0, K%32==0 hold for every call site.
template <int EPI, bool OUTBF, bool ACC>
__global__ __launch_bounds__(256) void gemm_bt(
    const u16* __restrict__ A, int lda,
    const u16* __restrict__ B, int ldb,
    void* __restrict__ Cout, int ldc,
    const float* __restrict__ bias,
    int M, int N, int K) {
  __shared__ __align__(16) u16 As[64 * 40];  // pad 32->40 shorts: 80B rows, 16B aligned
  __shared__ __align__(16) u16 Bs[64 * 40];
  const int t = threadIdx.x;
  const int n0 = blockIdx.x * 64, m0 = blockIdx.y * 64;
  const int wave = t >> 6, lane = t & 63;
  const int wm = (wave >> 1) * 32, wn = (wave & 1) * 32;
  const int quad = lane >> 4, r16 = lane & 15;
  const int srow = t >> 2, scol = (t & 3) * 8;
  f32x4 acc[2][2] = {};
  const u16* ap = A + (size_t)(m0 + srow) * lda + scol;
  const u16* bp = B + (size_t)(n0 + srow) * ldb + scol;
  for (int k0 = 0; k0 < K; k0 += 32) {
    uint4 av = *(const uint4*)(ap + k0);
    uint4 bv = *(const uint4*)(bp + k0);
    __syncthreads();
    *(uint4*)&As[srow * 40 + scol] = av;
    *(uint4*)&Bs[srow * 40 + scol] = bv;
    __syncthreads();
    bf16x8 a0 = *(const bf16x8*)&As[(wm + r16) * 40 + quad * 8];
    bf16x8 a1 = *(const bf16x8*)&As[(wm + 16 + r16) * 40 + quad * 8];
    bf16x8 b0 = *(const bf16x8*)&Bs[(wn + r16) * 40 + quad * 8];
    bf16x8 b1 = *(const bf16x8*)&Bs[(wn + 16 + r16) * 40 + quad * 8];
    acc[0][0] = __builtin_amdgcn_mfma_f32_16x16x32_bf16(a0, b0, acc[0][0], 0, 0, 0);
    acc[0][1] = __builtin_amdgcn_mfma_f32_16x16x32_bf16(a0, b1, acc[0][1], 0, 0, 0);
    acc[1][0] = __builtin_amdgcn_mfma_f32_16x16x32_bf16(a1, b0, acc[1][0], 0, 0, 0);
    acc[1][1] = __builtin_amdgcn_mfma_f32_16x16x32_bf16(a1, b1, acc[1][1], 0, 0, 0);
  }
  // C/D layout (m89/m91-verified): row = quad*4 + reg, col = lane&15
  for (int mi = 0; mi < 2; mi++)
    for (int ni = 0; ni < 2; ni++)
      for (int r = 0; r < 4; r++) {
        int gm = m0 + wm + mi * 16 + quad * 4 + r;
        int gn = n0 + wn + ni * 16 + r16;
        float v = acc[mi][ni][r];
        size_t idx = (size_t)gm * ldc + gn;
        if (ACC) v += ((float*)Cout)[idx];
        if (bias) v += bias[gn];
        if (EPI == 1) v = fmaxf(v, 0.0f);
        if (EPI == 2) v = tanhf(v);
        if (OUTBF) ((u16*)Cout)[idx] = f2b(v);
        else ((float*)Cout)[idx] = v;
      }
}

// ---------------- cosine matrix, hi/lo bf16 split ----------------
__global__ __launch_bounds__(256) void k_cos(u16* __restrict__ Chi, u16* __restrict__ Clo) {
  int gid = blockIdx.x * 256 + threadIdx.x;  // 1024*1024
  int k = gid >> 10, n = gid & 1023;
  int m = (k * n) & 1023;
  float c = cospif((float)m * (1.0f / 512.0f));  // cos(2*pi*m/1024)
  u16 hi = f2b(c);
  Chi[gid] = hi;
  Clo[gid] = f2b(c - b2f(hi));
}

// ---------------- window extraction (w,s order), hi/lo bf16 split ----------------
__global__ __launch_bounds__(256) void k_win(const float* __restrict__ x,
                                             u16* __restrict__ Whi, u16* __restrict__ Wlo) {
  int gid = blockIdx.x * 256 + threadIdx.x;  // 8064*1024/4
  int e = gid * 4;
  int r = e >> 10, n = e & 1023;
  int wI = r >> 7, s = r & 127;
  const float* src = x + (size_t)s * 32768 + wI * 512 + n;
  float4 v = *(const float4*)src;
  float vv[4] = {v.x, v.y, v.z, v.w};
#pragma unroll
  for (int i = 0; i < 4; i++) {
    u16 hi = f2b(vv[i]);
    Whi[e + i] = hi;
    Wlo[e + i] = f2b(vv[i] - b2f(hi));
  }
}

// ---------------- fp32 -> bf16 ----------------
__global__ __launch_bounds__(256) void k_f2bk(const float* __restrict__ src, u16* __restrict__ dst) {
  int gid = blockIdx.x * 256 + threadIdx.x;
  int i = gid * 4;
  float4 v = *(const float4*)(src + i);
  dst[i] = f2b(v.x); dst[i + 1] = f2b(v.y); dst[i + 2] = f2b(v.z); dst[i + 3] = f2b(v.w);
}

// ---------------- permute F (w,s)->(s,w) order ----------------
__global__ __launch_bounds__(256) void k_perm(const u16* __restrict__ F1, u16* __restrict__ F2) {
  int gid = blockIdx.x * 256 + threadIdx.x;  // 8064*128
  int ro = gid >> 7, n8 = (gid & 127) * 8;
  int s = ro / 63, wI = ro % 63;
  *(uint4*)&F2[(size_t)ro * 1024 + n8] = *(const uint4*)&F1[(size_t)(wI * 128 + s) * 1024 + n8];
}

// ---------------- Bcat = [Whh_e | Wih_e] bf16 (4096 x 2048) ----------------
__global__ __launch_bounds__(256) void k_bcat(const float* __restrict__ Whh,
                                              const float* __restrict__ Wih,
                                              u16* __restrict__ Bc) {
  int gid = blockIdx.x * 256 + threadIdx.x;  // 4096*2048/4
  int e = gid * 4;
  int r = e >> 11, c = e & 2047;
  const float* src = (c < 1024) ? (Whh + (size_t)r * 1024 + c) : (Wih + (size_t)r * 1024 + (c - 1024));
  float4 v = *(const float4*)src;
  Bc[e] = f2b(v.x); Bc[e + 1] = f2b(v.y); Bc[e + 2] = f2b(v.z); Bc[e + 3] = f2b(v.w);
}

// ---------------- copy F_t into right half of A_t ----------------
__global__ __launch_bounds__(256) void k_copyF(const u16* __restrict__ F1, u16* __restrict__ At, int t0) {
  int gid = blockIdx.x * 256 + threadIdx.x;  // 128*128
  int s = gid >> 7, n8 = (gid & 127) * 8;
  *(uint4*)&At[(size_t)s * 2048 + 1024 + n8] =
      *(const uint4*)&F1[(size_t)(t0 * 128 + s) * 1024 + n8];
}

// ---------------- encoder LSTM cell ----------------
__global__ __launch_bounds__(256) void k_cell_enc(const float* __restrict__ g,
                                                  float* __restrict__ c_e,
                                                  u16* __restrict__ At) {
  int gid = blockIdx.x * 256 + threadIdx.x;  // 128*1024
  int s = gid >> 10, j = gid & 1023;
  const float* gr = g + (size_t)s * 4096;
  float iv = sigmoidf_(gr[j]);
  float fv = sigmoidf_(gr[j + 1024]);
  float gv = tanhf(gr[j + 2048]);
  float ov = sigmoidf_(gr[j + 3072]);
  float c = fv * c_e[gid] + iv * gv;
  c_e[gid] = c;
  At[(size_t)s * 2048 + j] = f2b(ov * tanhf(c));  // h (bf16) into left half of A_t
}

// ---------------- decoder init ----------------
__global__ void k_initdec(const float* __restrict__ hmid, float* __restrict__ hbuf,
                          unsigned* __restrict__ cnt) {
  int gid = blockIdx.x * blockDim.x + threadIdx.x;
  if (gid < 1024) {
    float v = hmid[gid];  // h_mid row 0
    hbuf[gid] = v;
    hbuf[1024 + gid] = v;
  }
  if (gid == 0) *cnt = 0u;
}

// ---------------- persistent decoder: 8064 sequential LSTM steps, batch 1 ----------------
// 128 blocks x 256 threads. Block b owns h indices j = b*8..b*8+7 (32 rows of Whh_d in VGPRs,
// fp32, 128 regs/thread). Double-buffered global h + one atomic grid barrier per step.
__global__ __launch_bounds__(256, 1) void dec_persist(
    const float* __restrict__ Whh, const u16* __restrict__ Gih,
    float* __restrict__ hbuf, float* __restrict__ hfinal,
    unsigned* __restrict__ cnt) {
  const int b = blockIdx.x, t = threadIdx.x;
  const int rloc = t >> 3, part = t & 7;   // row 0..31, k-part 0..7
  const int q = rloc >> 3, jj = rloc & 7;  // gate 0..3, j-offset 0..7
  const int R = q * 1024 + (b * 8 + jj);
  // weights rotated by part*4 within the 128-chunk to kill LDS bank conflicts
  float4 wr[32];
  const float* Wrow = Whh + (size_t)R * 1024 + part * 128;
#pragma unroll
  for (int i = 0; i < 32; i++) {
    int off = (i * 4 + part * 4) & 127;
    wr[i] = *(const float4*)(Wrow + off);
  }
  __shared__ __align__(16) float hs[1024];
  __shared__ float gsum[32];
  __shared__ float cst[8];
  if (t < 8) cst[t] = hbuf[b * 8 + t];  // c init = h0 (only owner block writes this slice)
  int rb = 0;
  unsigned target = 0;
  for (int s = 0; s < 128; s++) {
    for (int wI = 0; wI < 63; wI++) {
      __syncthreads();
      *(float4*)&hs[t * 4] = *(const float4*)&hbuf[rb * 1024 + t * 4];
      float4 Uv = make_float4(0.f, 0.f, 0.f, 0.f);
      if (t < 8) {  // prefetch precomputed Wih_d-projection + bias for this step
        const u16* Ur = Gih + (size_t)(s * 63 + wI) * 4096 + (b * 8 + t);
        Uv.x = b2f(Ur[0]); Uv.y = b2f(Ur[1024]); Uv.z = b2f(Ur[2048]); Uv.w = b2f(Ur[3072]);
      }
      __syncthreads();
      const float* hp = hs + part * 128;
      float sum = 0.f;
#pragma unroll
      for (int i = 0; i < 32; i++) {
        int off = (i * 4 + part * 4) & 127;
        float4 hv = *(const float4*)(hp + off);
        sum += wr[i].x * hv.x + wr[i].y * hv.y + wr[i].z * hv.z + wr[i].w * hv.w;
      }
      sum += __shfl_xor(sum, 1);
      sum += __shfl_xor(sum, 2);
      sum += __shfl_xor(sum, 4);
      if (part == 0) gsum[rloc] = sum;
      __syncthreads();
      if (t < 8) {
        float gi = gsum[0 + t] + Uv.x;
        float gf = gsum[8 + t] + Uv.y;
        float gg = gsum[16 + t] + Uv.z;
        float go = gsum[24 + t] + Uv.w;
        float iv = sigmoidf_(gi), fv = sigmoidf_(gf), gv = tanhf(gg), ov = sigmoidf_(go);
        float c = fv * cst[t] + iv * gv;
        cst[t] = c;
        float h = ov * tanhf(c);
        hbuf[(rb ^ 1) * 1024 + b * 8 + t] = h;
        if (wI == 62) hfinal[(size_t)s * 1024 + b * 8 + t] = h;
        __threadfence();  // release our h slice device-wide
      }
      __syncthreads();
      target += 128u;
      if (t == 0) {
        atomicAdd(cnt, 1u);
        while (__hip_atomic_load(cnt, __ATOMIC_ACQUIRE, __HIP_MEMORY_SCOPE_AGENT) < target) {
          __builtin_amdgcn_s_sleep(1);
        }
      }
      __syncthreads();
      rb ^= 1;
    }
  }
}

// ---------------- row-wise log_softmax ----------------
__global__ __launch_bounds__(256) void k_lsm(const float* __restrict__ logits, float* __restrict__ out) {
  int s = blockIdx.x, t = threadIdx.x;
  const float* L = logits + (size_t)s * 1024;
  __shared__ float red[4], red2[4];
  float m = -1e30f;
  for (int i = t; i < 1024; i += 256) m = fmaxf(m, L[i]);
  for (int o = 1; o < 64; o <<= 1) m = fmaxf(m, __shfl_xor(m, o));
  if ((t & 63) == 0) red[t >> 6] = m;
  __syncthreads();
  m = fmaxf(fmaxf(red[0], red[1]), fmaxf(red[2], red[3]));
  float sum = 0.f;
  for (int i = t; i < 1024; i += 256) sum += expf(L[i] - m);
  for (int o = 1; o < 64; o <<= 1) sum += __shfl_xor(sum, o);
  if ((t & 63) == 0) red2[t >> 6] = sum;
  __syncthreads();
  sum = red2[0] + red2[1] + red2[2] + red2[3];
  float lse = m + logf(sum);
  for (int i = t; i < 1024; i += 256) out[(size_t)s * 1024 + i] = L[i] - lse;
}

extern "C" void kernel_launch(void* const* d_in, const int* in_sizes, int n_in,
                              void* d_out, int out_size, void* d_ws, size_t ws_size,
                              hipStream_t stream) {
  const float* x     = (const float*)d_in[0];
  const float* Wih_e = (const float*)d_in[1];
  const float* Whh_e = (const float*)d_in[2];
  const float* b_e   = (const float*)d_in[3];
  const float* Wm1   = (const float*)d_in[4];
  const float* bm1   = (const float*)d_in[5];
  const float* Wm2   = (const float*)d_in[6];
  const float* bm2   = (const float*)d_in[7];
  const float* Wih_d = (const float*)d_in[8];
  const float* Whh_d = (const float*)d_in[9];
  const float* b_d   = (const float*)d_in[10];
  const float* Wo    = (const float*)d_in[11];
  const float* bo    = (const float*)d_in[12];
  float* out = (float*)d_out;

  char* w = (char*)d_ws;
  size_t off = 0;
  auto alloc = [&](size_t bytes) { size_t r = off; off += (bytes + 255) & ~(size_t)255; return r; };
  u16* Chi = (u16*)(w + alloc((size_t)1024 * 1024 * 2));
  u16* Clo = (u16*)(w + alloc((size_t)1024 * 1024 * 2));
  u16* F1  = (u16*)(w + alloc((size_t)8064 * 1024 * 2));
  char* f2slot = w + alloc((size_t)8064 * 1024 * 2);   // Win_hi, later F2
  u16* WinHi = (u16*)f2slot;
  u16* F2    = (u16*)f2slot;
  char* bcslot = w + alloc((size_t)4096 * 2048 * 2);   // Win_lo, later Bcat
  u16* WinLo = (u16*)bcslot;
  u16* Bcat  = (u16*)bcslot;
  char* gislot = w + alloc((size_t)8064 * 4096 * 2);   // Fgem (fp32, 33MB), later Gih_d (bf16, 66MB)
  float* Fgem = (float*)gislot;
  u16* Gih    = (u16*)gislot;
  u16* Wihd = (u16*)(w + alloc((size_t)4096 * 1024 * 2));
  u16* Wm1b = (u16*)(w + alloc((size_t)1024 * 1024 * 2));
  u16* Wm2b = (u16*)(w + alloc((size_t)1024 * 1024 * 2));
  u16* Wob  = (u16*)(w + alloc((size_t)1024 * 1024 * 2));
  u16* At   = (u16*)(w + alloc((size_t)128 * 2048 * 2));
  float* Ge = (float*)(w + alloc((size_t)128 * 4096 * 4));
  float* Ce = (float*)(w + alloc((size_t)128 * 1024 * 4));
  u16* Mid1 = (u16*)(w + alloc((size_t)128 * 1024 * 2));
  float* Hmid = (float*)(w + alloc((size_t)128 * 1024 * 4));
  float* Hbuf = (float*)(w + alloc((size_t)2048 * 4));
  unsigned* Cnt = (unsigned*)(w + alloc(256));
  float* Hfin = (float*)(w + alloc((size_t)128 * 1024 * 4));
  u16* Hfinb  = (u16*)(w + alloc((size_t)128 * 1024 * 2));
  float* Logit = (float*)(w + alloc((size_t)128 * 1024 * 4));
  (void)ws_size; (void)in_sizes; (void)n_in; (void)out_size;

  // zero-init A_t (h=0 for encoder step 0) and c_e
  hipMemsetAsync(At, 0, (size_t)128 * 2048 * 2, stream);
  hipMemsetAsync(Ce, 0, (size_t)128 * 1024 * 4, stream);

  // Fourier features: F = windows @ C, hi/lo split for ~fp32 accuracy
  k_cos<<<4096, 256, 0, stream>>>(Chi, Clo);
  k_win<<<8064, 256, 0, stream>>>(x, WinHi, WinLo);
  gemm_bt<0, false, false><<<dim3(16, 126), 256, 0, stream>>>(WinHi, 1024, Chi, 1024, Fgem, 1024, nullptr, 8064, 1024, 1024);
  gemm_bt<0, false, true><<<dim3(16, 126), 256, 0, stream>>>(WinHi, 1024, Clo, 1024, Fgem, 1024, nullptr, 8064, 1024, 1024);
  gemm_bt<0, false, true><<<dim3(16, 126), 256, 0, stream>>>(WinLo, 1024, Chi, 1024, Fgem, 1024, nullptr, 8064, 1024, 1024);
  k_f2bk<<<8064, 256, 0, stream>>>(Fgem, F1);        // F1 bf16, (w,s) order
  k_perm<<<4032, 256, 0, stream>>>(F1, F2);          // F2 bf16, (s,w) order (overwrites WinHi slot)

  // weight conversions
  k_f2bk<<<4096, 256, 0, stream>>>(Wih_d, Wihd);
  k_f2bk<<<1024, 256, 0, stream>>>(Wm1, Wm1b);
  k_f2bk<<<1024, 256, 0, stream>>>(Wm2, Wm2b);
  k_f2bk<<<1024, 256, 0, stream>>>(Wo, Wob);
  k_bcat<<<8192, 256, 0, stream>>>(Whh_e, Wih_e, Bcat);  // overwrites WinLo slot (dead)

  // decoder input projection for all 8064 steps: Gih = F2 @ Wih_d^T + b_d (bf16)
  gemm_bt<0, true, false><<<dim3(64, 126), 256, 0, stream>>>(F2, 1024, Wihd, 1024, Gih, 4096, b_d, 8064, 4096, 1024);

  // encoder: 63 steps of gates = [h | F_t] @ [Whh_e | Wih_e]^T + b_e, then cell
  for (int t = 0; t < 63; t++) {
    k_copyF<<<64, 256, 0, stream>>>(F1, At, t);
    gemm_bt<0, false, false><<<dim3(64, 2), 256, 0, stream>>>(At, 2048, Bcat, 2048, Ge, 4096, b_e, 128, 4096, 2048);
    k_cell_enc<<<512, 256, 0, stream>>>(Ge, Ce, At);
  }

  // mid MLP: tanh(relu(h_enc @ Wm1^T + bm1) @ Wm2^T + bm2)
  gemm_bt<1, true, false><<<dim3(16, 2), 256, 0, stream>>>(At, 2048, Wm1b, 1024, Mid1, 1024, bm1, 128, 1024, 1024);
  gemm_bt<2, false, false><<<dim3(16, 2), 256, 0, stream>>>(Mid1, 1024, Wm2b, 1024, Hmid, 1024, bm2, 128, 1024, 1024);

  // decoder
  k_initdec<<<4, 256, 0, stream>>>(Hmid, Hbuf, Cnt);
  dec_persist<<<128, 256, 0, stream>>>(Whh_d, Gih, Hbuf, Hfin, Cnt);

  // output head: log_softmax(h_final @ Wo^T + bo)
  k_f2bk<<<128, 256, 0, stream>>>(Hfin, Hfinb);
  gemm_bt<0, false, false><<<dim3(16, 2), 256, 0, stream>>>(Hfinb, 1024, Wob, 1024, Logit, 1024, bo, 128, 1024, 1024);
  k_lsm<<<128, 256, 0, stream>>>(Logit, out);
}

// Round 2
// 23425.262 us; speedup vs baseline: 2.6114x; 2.6114x over previous
//
#include <hip/hip_runtime.h>

typedef unsigned short u16;
typedef __bf16 bf16x8 __attribute__((ext_vector_type(8)));
typedef float f32x4 __attribute__((ext_vector_type(4)));
typedef unsigned long long u64;

__device__ __forceinline__ u16 f2b(float f) {
  unsigned u = __builtin_bit_cast(unsigned, f);
  u = (u + 0x7FFFu + ((u >> 16) & 1u)) >> 16;
  return (u16)u;
}
__device__ __forceinline__ float b2f(u16 h) {
  return __builtin_bit_cast(float, ((unsigned)h) << 16);
}
__device__ __forceinline__ float sigmoidf_(float x) { return 1.0f / (1.0f + expf(-x)); }
__device__ __forceinline__ float loF(u64 v) {
  return __builtin_bit_cast(float, (unsigned)(v & 0xFFFFFFFFull));
}
__device__ __forceinline__ u64 packHV(float h, unsigned tag) {
  return ((u64)tag << 32) | (u64)__builtin_bit_cast(unsigned, h);
}
__device__ __forceinline__ u64 aload(const u64* p) {
  return __hip_atomic_load(p, __ATOMIC_RELAXED, __HIP_MEMORY_SCOPE_AGENT);
}

// ---------------- generic bf16 MFMA GEMM: C[M,N] = A[M,K] @ B[N,K]^T (+C) (+bias) ----------------
template <int EPI, bool OUTBF, bool ACC>
__global__ __launch_bounds__(256) void gemm_bt(
    const u16* __restrict__ A, int lda,
    const u16* __restrict__ B, int ldb,
    void* __restrict__ Cout, int ldc,
    const float* __restrict__ bias,
    int M, int N, int K) {
  __shared__ __align__(16) u16 As[64 * 40];
  __shared__ __align__(16) u16 Bs[64 * 40];
  const int t = threadIdx.x;
  const int n0 = blockIdx.x * 64, m0 = blockIdx.y * 64;
  const int wave = t >> 6, lane = t & 63;
  const int wm = (wave >> 1) * 32, wn = (wave & 1) * 32;
  const int quad = lane >> 4, r16 = lane & 15;
  const int srow = t >> 2, scol = (t & 3) * 8;
  f32x4 acc[2][2] = {};
  const u16* ap = A + (size_t)(m0 + srow) * lda + scol;
  const u16* bp = B + (size_t)(n0 + srow) * ldb + scol;
  for (int k0 = 0; k0 < K; k0 += 32) {
    uint4 av = *(const uint4*)(ap + k0);
    uint4 bv = *(const uint4*)(bp + k0);
    __syncthreads();
    *(uint4*)&As[srow * 40 + scol] = av;
    *(uint4*)&Bs[srow * 40 + scol] = bv;
    __syncthreads();
    bf16x8 a0 = *(const bf16x8*)&As[(wm + r16) * 40 + quad * 8];
    bf16x8 a1 = *(const bf16x8*)&As[(wm + 16 + r16) * 40 + quad * 8];
    bf16x8 b0 = *(const bf16x8*)&Bs[(wn + r16) * 40 + quad * 8];
    bf16x8 b1 = *(const bf16x8*)&Bs[(wn + 16 + r16) * 40 + quad * 8];
    acc[0][0] = __builtin_amdgcn_mfma_f32_16x16x32_bf16(a0, b0, acc[0][0], 0, 0, 0);
    acc[0][1] = __builtin_amdgcn_mfma_f32_16x16x32_bf16(a0, b1, acc[0][1], 0, 0, 0);
    acc[1][0] = __builtin_amdgcn_mfma_f32_16x16x32_bf16(a1, b0, acc[1][0], 0, 0, 0);
    acc[1][1] = __builtin_amdgcn_mfma_f32_16x16x32_bf16(a1, b1, acc[1][1], 0, 0, 0);
  }
  for (int mi = 0; mi < 2; mi++)
    for (int ni = 0; ni < 2; ni++)
      for (int r = 0; r < 4; r++) {
        int gm = m0 + wm + mi * 16 + quad * 4 + r;
        int gn = n0 + wn + ni * 16 + r16;
        float v = acc[mi][ni][r];
        size_t idx = (size_t)gm * ldc + gn;
        if (ACC) v += ((float*)Cout)[idx];
        if (bias) v += bias[gn];
        if (EPI == 1) v = fmaxf(v, 0.0f);
        if (EPI == 2) v = tanhf(v);
        if (OUTBF) ((u16*)Cout)[idx] = f2b(v);
        else ((float*)Cout)[idx] = v;
      }
}

// ---------------- cosine matrix, hi/lo bf16 split ----------------
__global__ __launch_bounds__(256) void k_cos(u16* __restrict__ Chi, u16* __restrict__ Clo) {
  int gid = blockIdx.x * 256 + threadIdx.x;
  int k = gid >> 10, n = gid & 1023;
  int m = (k * n) & 1023;
  float c = cospif((float)m * (1.0f / 512.0f));
  u16 hi = f2b(c);
  Chi[gid] = hi;
  Clo[gid] = f2b(c - b2f(hi));
}

// ---------------- window extraction (w,s order), hi/lo bf16 split ----------------
__global__ __launch_bounds__(256) void k_win(const float* __restrict__ x,
                                             u16* __restrict__ Whi, u16* __restrict__ Wlo) {
  int gid = blockIdx.x * 256 + threadIdx.x;
  int e = gid * 4;
  int r = e >> 10, n = e & 1023;
  int wI = r >> 7, s = r & 127;
  const float* src = x + (size_t)s * 32768 + wI * 512 + n;
  float4 v = *(const float4*)src;
  float vv[4] = {v.x, v.y, v.z, v.w};
#pragma unroll
  for (int i = 0; i < 4; i++) {
    u16 hi = f2b(vv[i]);
    Whi[e + i] = hi;
    Wlo[e + i] = f2b(vv[i] - b2f(hi));
  }
}

// ---------------- fp32 -> bf16 ----------------
__global__ __launch_bounds__(256) void k_f2bk(const float* __restrict__ src, u16* __restrict__ dst) {
  int gid = blockIdx.x * 256 + threadIdx.x;
  int i = gid * 4;
  float4 v = *(const float4*)(src + i);
  dst[i] = f2b(v.x); dst[i + 1] = f2b(v.y); dst[i + 2] = f2b(v.z); dst[i + 3] = f2b(v.w);
}

// ---------------- permute F (w,s)->(s,w) order ----------------
__global__ __launch_bounds__(256) void k_perm(const u16* __restrict__ F1, u16* __restrict__ F2) {
  int gid = blockIdx.x * 256 + threadIdx.x;
  int ro = gid >> 7, n8 = (gid & 127) * 8;
  int s = ro / 63, wI = ro % 63;
  *(uint4*)&F2[(size_t)ro * 1024 + n8] = *(const uint4*)&F1[(size_t)(wI * 128 + s) * 1024 + n8];
}

// ---------------- encoder LSTM cell (adds precomputed input projection) ----------------
__global__ __launch_bounds__(256) void k_cell_enc(const float* __restrict__ g,
                                                  const u16* __restrict__ gihe, int t0,
                                                  float* __restrict__ c_e,
                                                  u16* __restrict__ At) {
  int gid = blockIdx.x * 256 + threadIdx.x;  // 128*1024
  int s = gid >> 10, j = gid & 1023;
  const float* gr = g + (size_t)s * 4096;
  const u16* er = gihe + (size_t)(t0 * 128 + s) * 4096;
  float iv = sigmoidf_(gr[j] + b2f(er[j]));
  float fv = sigmoidf_(gr[j + 1024] + b2f(er[j + 1024]));
  float gv = tanhf(gr[j + 2048] + b2f(er[j + 2048]));
  float ov = sigmoidf_(gr[j + 3072] + b2f(er[j + 3072]));
  float c = fv * c_e[gid] + iv * gv;
  c_e[gid] = c;
  At[(size_t)s * 1024 + j] = f2b(ov * tanhf(c));
}

// ---------------- decoder init: both h buffers, tagged ----------------
__global__ void k_initdec(const float* __restrict__ hmid, u64* __restrict__ hb) {
  int gid = blockIdx.x * blockDim.x + threadIdx.x;  // 2048
  if (gid < 1024) {
    hb[gid] = packHV(hmid[gid], 0u);               // buffer 0: h_0, tag 0
  } else if (gid < 2048) {
    hb[gid] = packHV(0.0f, 0xFFFFFFFFu);           // buffer 1: sentinel tag
  }
}

// ---------------- persistent decoder: tag-in-data sync, no atomics, no fences ----------------
// 128 blocks x 256 threads. Block b owns h[b*8..b*8+8). h exchanged as {f32,u32 tag} u64
// words via relaxed agent-scope atomics (write-through L3). Double-buffer lockstep:
// all tags==n present => all blocks wrote h_n => all blocks done reading h_{n-1}.
__global__ __launch_bounds__(256, 1) void dec_persist(
    const float* __restrict__ Whh, const u16* __restrict__ Gih,
    u64* __restrict__ hb, float* __restrict__ hfinal) {
  const int b = blockIdx.x, t = threadIdx.x;
  const int rloc = t >> 3, part = t & 7;   // row 0..31, k-part 0..7
  const int q = rloc >> 3, jj = rloc & 7;  // gate 0..3, j-offset 0..7
  const int R = q * 1024 + (b * 8 + jj);
  float4 wr[32];
  const float* Wrow = Whh + (size_t)R * 1024 + part * 128;
#pragma unroll
  for (int i = 0; i < 32; i++) {
    int off = (i * 4 + part * 4) & 127;
    wr[i] = *(const float4*)(Wrow + off);
  }
  __shared__ __align__(16) float hs[1024];
  __shared__ float gsum[32];
  __shared__ float cst[8];
  if (t < 8) cst[t] = loF(aload(&hb[b * 8 + t]));  // c init = h0
  int n = 0;
  for (int s = 0; s < 128; s++) {
    for (int wI = 0; wI < 63; wI++, n++) {
      // prefetch input projection (independent of h)
      float4 Uv = make_float4(0.f, 0.f, 0.f, 0.f);
      if (t < 8) {
        const u16* Ur = Gih + (size_t)n * 4096 + (b * 8 + t);
        Uv.x = b2f(Ur[0]); Uv.y = b2f(Ur[1024]); Uv.z = b2f(Ur[2048]); Uv.w = b2f(Ur[3072]);
      }
      // poll own 4 words of h_n
      const u64* hp_g = hb + (size_t)(n & 1) * 1024 + 4 * t;
      const unsigned tn = (unsigned)n;
      u64 v0, v1, v2, v3;
      for (;;) {
        v0 = aload(hp_g + 0); v1 = aload(hp_g + 1);
        v2 = aload(hp_g + 2); v3 = aload(hp_g + 3);
        bool ok = ((unsigned)(v0 >> 32) == tn) & ((unsigned)(v1 >> 32) == tn) &
                  ((unsigned)(v2 >> 32) == tn) & ((unsigned)(v3 >> 32) == tn);
        if (ok) break;
        __builtin_amdgcn_s_sleep(1);
      }
      __syncthreads();  // B1: prev-iter LDS consumers done
      *(float4*)&hs[4 * t] = make_float4(loF(v0), loF(v1), loF(v2), loF(v3));
      __syncthreads();  // B2: hs ready
      const float* hp = hs + part * 128;
      float sum = 0.f;
#pragma unroll
      for (int i = 0; i < 32; i++) {
        int off = (i * 4 + part * 4) & 127;
        float4 hv = *(const float4*)(hp + off);
        sum += wr[i].x * hv.x + wr[i].y * hv.y + wr[i].z * hv.z + wr[i].w * hv.w;
      }
      sum += __shfl_xor(sum, 1);
      sum += __shfl_xor(sum, 2);
      sum += __shfl_xor(sum, 4);
      if (part == 0) gsum[rloc] = sum;
      __syncthreads();  // B3: gsum ready
      if (t < 8) {
        float gi = gsum[0 + t] + Uv.x;
        float gf = gsum[8 + t] + Uv.y;
        float gg = gsum[16 + t] + Uv.z;
        float go = gsum[24 + t] + Uv.w;
        float iv = sigmoidf_(gi), fv = sigmoidf_(gf), gv = tanhf(gg), ov = sigmoidf_(go);
        float c = fv * cst[t] + iv * gv;
        cst[t] = c;
        float h = ov * tanhf(c);
        __hip_atomic_store(&hb[(size_t)((n + 1) & 1) * 1024 + b * 8 + t],
                           packHV(h, (unsigned)(n + 1)),
                           __ATOMIC_RELAXED, __HIP_MEMORY_SCOPE_AGENT);
        if (wI == 62) hfinal[(size_t)s * 1024 + b * 8 + t] = h;
      }
    }
  }
}

// ---------------- row-wise log_softmax ----------------
__global__ __launch_bounds__(256) void k_lsm(const float* __restrict__ logits, float* __restrict__ out) {
  int s = blockIdx.x, t = threadIdx.x;
  const float* L = logits + (size_t)s * 1024;
  __shared__ float red[4], red2[4];
  float m = -1e30f;
  for (int i = t; i < 1024; i += 256) m = fmaxf(m, L[i]);
  for (int o = 1; o < 64; o <<= 1) m = fmaxf(m, __shfl_xor(m, o));
  if ((t & 63) == 0) red[t >> 6] = m;
  __syncthreads();
  m = fmaxf(fmaxf(red[0], red[1]), fmaxf(red[2], red[3]));
  float sum = 0.f;
  for (int i = t; i < 1024; i += 256) sum += expf(L[i] - m);
  for (int o = 1; o < 64; o <<= 1) sum += __shfl_xor(sum, o);
  if ((t & 63) == 0) red2[t >> 6] = sum;
  __syncthreads();
  sum = red2[0] + red2[1] + red2[2] + red2[3];
  float lse = m + logf(sum);
  for (int i = t; i < 1024; i += 256) out[(size_t)s * 1024 + i] = L[i] - lse;
}

extern "C" void kernel_launch(void* const* d_in, const int* in_sizes, int n_in,
                              void* d_out, int out_size, void* d_ws, size_t ws_size,
                              hipStream_t stream) {
  const float* x     = (const float*)d_in[0];
  const float* Wih_e = (const float*)d_in[1];
  const float* Whh_e = (const float*)d_in[2];
  const float* b_e   = (const float*)d_in[3];
  const float* Wm1   = (const float*)d_in[4];
  const float* bm1   = (const float*)d_in[5];
  const float* Wm2   = (const float*)d_in[6];
  const float* bm2   = (const float*)d_in[7];
  const float* Wih_d = (const float*)d_in[8];
  const float* Whh_d = (const float*)d_in[9];
  const float* b_d   = (const float*)d_in[10];
  const float* Wo    = (const float*)d_in[11];
  const float* bo    = (const float*)d_in[12];
  float* out = (float*)d_out;

  char* w = (char*)d_ws;
  size_t off = 0;
  auto alloc = [&](size_t bytes) { size_t r = off; off += (bytes + 255) & ~(size_t)255; return r; };
  u16* Chi = (u16*)(w + alloc((size_t)1024 * 1024 * 2));
  u16* Clo = (u16*)(w + alloc((size_t)1024 * 1024 * 2));
  u16* F1  = (u16*)(w + alloc((size_t)8064 * 1024 * 2));
  char* f2slot = w + alloc((size_t)8064 * 1024 * 2);   // Win_hi, later F2
  u16* WinHi = (u16*)f2slot;
  u16* F2    = (u16*)f2slot;
  u16* WinLo = (u16*)(w + alloc((size_t)8064 * 1024 * 2));
  char* gislot = w + alloc((size_t)8064 * 4096 * 2);   // Fgem (fp32 33MB), later Gih_d (bf16 66MB)
  float* Fgem = (float*)gislot;
  u16* Gih    = (u16*)gislot;
  u16* Gihe = (u16*)(w + alloc((size_t)8064 * 4096 * 2));  // encoder input projections (bf16)
  u16* Wihd  = (u16*)(w + alloc((size_t)4096 * 1024 * 2));
  u16* Wihe  = (u16*)(w + alloc((size_t)4096 * 1024 * 2));
  u16* Whhe  = (u16*)(w + alloc((size_t)4096 * 1024 * 2));
  u16* Wm1b = (u16*)(w + alloc((size_t)1024 * 1024 * 2));
  u16* Wm2b = (u16*)(w + alloc((size_t)1024 * 1024 * 2));
  u16* Wob  = (u16*)(w + alloc((size_t)1024 * 1024 * 2));
  u16* At   = (u16*)(w + alloc((size_t)128 * 1024 * 2));
  float* Ge = (float*)(w + alloc((size_t)128 * 4096 * 4));
  float* Ce = (float*)(w + alloc((size_t)128 * 1024 * 4));
  u16* Mid1 = (u16*)(w + alloc((size_t)128 * 1024 * 2));
  float* Hmid = (float*)(w + alloc((size_t)128 * 1024 * 4));
  u64* Hb = (u64*)(w + alloc((size_t)2048 * 8));
  float* Hfin = (float*)(w + alloc((size_t)128 * 1024 * 4));
  u16* Hfinb  = (u16*)(w + alloc((size_t)128 * 1024 * 2));
  float* Logit = (float*)(w + alloc((size_t)128 * 1024 * 4));
  (void)ws_size; (void)in_sizes; (void)n_in; (void)out_size;

  hipMemsetAsync(At, 0, (size_t)128 * 1024 * 2, stream);   // h=0 for encoder step 0
  hipMemsetAsync(Ce, 0, (size_t)128 * 1024 * 4, stream);

  // Fourier features: F = windows @ C, hi/lo split for ~fp32 accuracy
  k_cos<<<4096, 256, 0, stream>>>(Chi, Clo);
  k_win<<<8064, 256, 0, stream>>>(x, WinHi, WinLo);
  gemm_bt<0, false, false><<<dim3(16, 126), 256, 0, stream>>>(WinHi, 1024, Chi, 1024, Fgem, 1024, nullptr, 8064, 1024, 1024);
  gemm_bt<0, false, true><<<dim3(16, 126), 256, 0, stream>>>(WinHi, 1024, Clo, 1024, Fgem, 1024, nullptr, 8064, 1024, 1024);
  gemm_bt<0, false, true><<<dim3(16, 126), 256, 0, stream>>>(WinLo, 1024, Chi, 1024, Fgem, 1024, nullptr, 8064, 1024, 1024);
  k_f2bk<<<8064, 256, 0, stream>>>(Fgem, F1);        // F1 bf16, (w,s) order
  k_perm<<<4032, 256, 0, stream>>>(F1, F2);          // F2 bf16, (s,w) order

  // weight conversions
  k_f2bk<<<4096, 256, 0, stream>>>(Wih_d, Wihd);
  k_f2bk<<<4096, 256, 0, stream>>>(Wih_e, Wihe);
  k_f2bk<<<4096, 256, 0, stream>>>(Whh_e, Whhe);
  k_f2bk<<<1024, 256, 0, stream>>>(Wm1, Wm1b);
  k_f2bk<<<1024, 256, 0, stream>>>(Wm2, Wm2b);
  k_f2bk<<<1024, 256, 0, stream>>>(Wo, Wob);

  // batched input projections: decoder Gih = F2 @ Wih_d^T + b_d; encoder Gihe = F1 @ Wih_e^T + b_e
  gemm_bt<0, true, false><<<dim3(64, 126), 256, 0, stream>>>(F2, 1024, Wihd, 1024, Gih, 4096, b_d, 8064, 4096, 1024);
  gemm_bt<0, true, false><<<dim3(64, 126), 256, 0, stream>>>(F1, 1024, Wihe, 1024, Gihe, 4096, b_e, 8064, 4096, 1024);

  // encoder: 63 steps of gates = h @ Whh_e^T (+Gihe in cell), then cell
  for (int t = 0; t < 63; t++) {
    gemm_bt<0, false, false><<<dim3(64, 2), 256, 0, stream>>>(At, 1024, Whhe, 1024, Ge, 4096, nullptr, 128, 4096, 1024);
    k_cell_enc<<<512, 256, 0, stream>>>(Ge, Gihe, t, Ce, At);
  }

  // mid MLP: tanh(relu(h_enc @ Wm1^T + bm1) @ Wm2^T + bm2)
  gemm_bt<1, true, false><<<dim3(16, 2), 256, 0, stream>>>(At, 1024, Wm1b, 1024, Mid1, 1024, bm1, 128, 1024, 1024);
  gemm_bt<2, false, false><<<dim3(16, 2), 256, 0, stream>>>(Mid1, 1024, Wm2b, 1024, Hmid, 1024, bm2, 128, 1024, 1024);

  // decoder
  k_initdec<<<8, 256, 0, stream>>>(Hmid, Hb);
  dec_persist<<<128, 256, 0, stream>>>(Whh_d, Gih, Hb, Hfin);

  // output head: log_softmax(h_final @ Wo^T + bo)
  k_f2bk<<<128, 256, 0, stream>>>(Hfin, Hfinb);
  gemm_bt<0, false, false><<<dim3(16, 2), 256, 0, stream>>>(Hfinb, 1024, Wob, 1024, Logit, 1024, bo, 128, 1024, 1024);
  k_lsm<<<128, 256, 0, stream>>>(Logit, out);
}

// Round 3
// 19211.641 us; speedup vs baseline: 3.1842x; 1.2193x over previous
//
#include <hip/hip_runtime.h>

typedef unsigned short u16;
typedef unsigned u32;
typedef unsigned long long u64;
typedef __bf16 bf16x8 __attribute__((ext_vector_type(8)));
typedef _Float16 half8 __attribute__((ext_vector_type(8)));
typedef float f32x4 __attribute__((ext_vector_type(4)));

__device__ __forceinline__ u16 f2b(float f) {
  unsigned u = __builtin_bit_cast(unsigned, f);
  u = (u + 0x7FFFu + ((u >> 16) & 1u)) >> 16;
  return (u16)u;
}
__device__ __forceinline__ float b2f(u16 h) {
  return __builtin_bit_cast(float, ((unsigned)h) << 16);
}
__device__ __forceinline__ u16 f2h(float f) {
  _Float16 h = (_Float16)f;
  return __builtin_bit_cast(unsigned short, h);
}
__device__ __forceinline__ float sigmoidf_(float x) { return 1.0f / (1.0f + expf(-x)); }
__device__ __forceinline__ u64 aload(const u64* p) {
  return __hip_atomic_load(p, __ATOMIC_RELAXED, __HIP_MEMORY_SCOPE_AGENT);
}

// ---------------- generic bf16 MFMA GEMM: C[M,N] = A[M,K] @ B[N,K]^T (+C) (+bias) ----------------
template <int EPI, bool OUTBF, bool ACC>
__global__ __launch_bounds__(256) void gemm_bt(
    const u16* __restrict__ A, int lda,
    const u16* __restrict__ B, int ldb,
    void* __restrict__ Cout, int ldc,
    const float* __restrict__ bias,
    int M, int N, int K) {
  __shared__ __align__(16) u16 As[64 * 40];
  __shared__ __align__(16) u16 Bs[64 * 40];
  const int t = threadIdx.x;
  const int n0 = blockIdx.x * 64, m0 = blockIdx.y * 64;
  const int wave = t >> 6, lane = t & 63;
  const int wm = (wave >> 1) * 32, wn = (wave & 1) * 32;
  const int quad = lane >> 4, r16 = lane & 15;
  const int srow = t >> 2, scol = (t & 3) * 8;
  f32x4 acc[2][2] = {};
  const u16* ap = A + (size_t)(m0 + srow) * lda + scol;
  const u16* bp = B + (size_t)(n0 + srow) * ldb + scol;
  for (int k0 = 0; k0 < K; k0 += 32) {
    uint4 av = *(const uint4*)(ap + k0);
    uint4 bv = *(const uint4*)(bp + k0);
    __syncthreads();
    *(uint4*)&As[srow * 40 + scol] = av;
    *(uint4*)&Bs[srow * 40 + scol] = bv;
    __syncthreads();
    bf16x8 a0 = *(const bf16x8*)&As[(wm + r16) * 40 + quad * 8];
    bf16x8 a1 = *(const bf16x8*)&As[(wm + 16 + r16) * 40 + quad * 8];
    bf16x8 b0 = *(const bf16x8*)&Bs[(wn + r16) * 40 + quad * 8];
    bf16x8 b1 = *(const bf16x8*)&Bs[(wn + 16 + r16) * 40 + quad * 8];
    acc[0][0] = __builtin_amdgcn_mfma_f32_16x16x32_bf16(a0, b0, acc[0][0], 0, 0, 0);
    acc[0][1] = __builtin_amdgcn_mfma_f32_16x16x32_bf16(a0, b1, acc[0][1], 0, 0, 0);
    acc[1][0] = __builtin_amdgcn_mfma_f32_16x16x32_bf16(a1, b0, acc[1][0], 0, 0, 0);
    acc[1][1] = __builtin_amdgcn_mfma_f32_16x16x32_bf16(a1, b1, acc[1][1], 0, 0, 0);
  }
  for (int mi = 0; mi < 2; mi++)
    for (int ni = 0; ni < 2; ni++)
      for (int r = 0; r < 4; r++) {
        int gm = m0 + wm + mi * 16 + quad * 4 + r;
        int gn = n0 + wn + ni * 16 + r16;
        float v = acc[mi][ni][r];
        size_t idx = (size_t)gm * ldc + gn;
        if (ACC) v += ((float*)Cout)[idx];
        if (bias) v += bias[gn];
        if (EPI == 1) v = fmaxf(v, 0.0f);
        if (EPI == 2) v = tanhf(v);
        if (OUTBF) ((u16*)Cout)[idx] = f2b(v);
        else ((float*)Cout)[idx] = v;
      }
}

// ---------------- cosine matrix, hi/lo bf16 split ----------------
__global__ __launch_bounds__(256) void k_cos(u16* __restrict__ Chi, u16* __restrict__ Clo) {
  int gid = blockIdx.x * 256 + threadIdx.x;
  int k = gid >> 10, n = gid & 1023;
  int m = (k * n) & 1023;
  float c = cospif((float)m * (1.0f / 512.0f));
  u16 hi = f2b(c);
  Chi[gid] = hi;
  Clo[gid] = f2b(c - b2f(hi));
}

// ---------------- window extraction (w,s order), hi/lo bf16 split ----------------
__global__ __launch_bounds__(256) void k_win(const float* __restrict__ x,
                                             u16* __restrict__ Whi, u16* __restrict__ Wlo) {
  int gid = blockIdx.x * 256 + threadIdx.x;
  int e = gid * 4;
  int r = e >> 10, n = e & 1023;
  int wI = r >> 7, s = r & 127;
  const float* src = x + (size_t)s * 32768 + wI * 512 + n;
  float4 v = *(const float4*)src;
  float vv[4] = {v.x, v.y, v.z, v.w};
#pragma unroll
  for (int i = 0; i < 4; i++) {
    u16 hi = f2b(vv[i]);
    Whi[e + i] = hi;
    Wlo[e + i] = f2b(vv[i] - b2f(hi));
  }
}

// ---------------- fp32 -> bf16 ----------------
__global__ __launch_bounds__(256) void k_f2bk(const float* __restrict__ src, u16* __restrict__ dst) {
  int gid = blockIdx.x * 256 + threadIdx.x;
  int i = gid * 4;
  float4 v = *(const float4*)(src + i);
  dst[i] = f2b(v.x); dst[i + 1] = f2b(v.y); dst[i + 2] = f2b(v.z); dst[i + 3] = f2b(v.w);
}

// ---------------- permute F (w,s)->(s,w) order ----------------
__global__ __launch_bounds__(256) void k_perm(const u16* __restrict__ F1, u16* __restrict__ F2) {
  int gid = blockIdx.x * 256 + threadIdx.x;
  int ro = gid >> 7, n8 = (gid & 127) * 8;
  int s = ro / 63, wI = ro % 63;
  *(uint4*)&F2[(size_t)ro * 1024 + n8] = *(const uint4*)&F1[(size_t)(wI * 128 + s) * 1024 + n8];
}

// ---------------- encoder LSTM cell (adds precomputed input projection) ----------------
__global__ __launch_bounds__(256) void k_cell_enc(const float* __restrict__ g,
                                                  const u16* __restrict__ gihe, int t0,
                                                  float* __restrict__ c_e,
                                                  u16* __restrict__ At) {
  int gid = blockIdx.x * 256 + threadIdx.x;  // 128*1024
  int s = gid >> 10, j = gid & 1023;
  const float* gr = g + (size_t)s * 4096;
  const u16* er = gihe + (size_t)(t0 * 128 + s) * 4096;
  float iv = sigmoidf_(gr[j] + b2f(er[j]));
  float fv = sigmoidf_(gr[j + 1024] + b2f(er[j + 1024]));
  float gv = tanhf(gr[j + 2048] + b2f(er[j + 2048]));
  float ov = sigmoidf_(gr[j + 3072] + b2f(er[j + 3072]));
  float c = fv * c_e[gid] + iv * gv;
  c_e[gid] = c;
  At[(size_t)s * 1024 + j] = f2b(ov * tanhf(c));
}

// ---------------- decoder init: h words = {tag | 2 x f16}, both buffers ----------------
__global__ void k_initdec(const float* __restrict__ hmid, u64* __restrict__ hb) {
  int gid = blockIdx.x * blockDim.x + threadIdx.x;  // 1024
  if (gid < 512) {
    u32 lo = (u32)f2h(hmid[2 * gid]) | ((u32)f2h(hmid[2 * gid + 1]) << 16);
    hb[gid] = (u64)lo;                              // buffer 0: h_0, tag 0
  } else if (gid < 1024) {
    hb[gid] = 0xFFFFFFFF00000000ull;                // buffer 1: sentinel tag
  }
}

// ---------------- persistent decoder: MFMA matvec + per-wave quarter polling ----------------
// 128 blocks x 256 threads (4 waves). Block b owns h[b*8..b*8+8). Whh rows for this block
// live in registers as f16 MFMA A-fragments (wave w covers k-quarter 256w..256w+256).
// h exchanged as 512 u64 words {tag(hi32) | 2xf16(lo32)} via relaxed agent atomics.
// Each wave polls only its own 128-word quarter; one __syncthreads per step for the
// cross-wave partial-sum reduction (double-buffered in LDS).
__global__ __launch_bounds__(256, 1) void dec_persist(
    const float* __restrict__ Whh, const u16* __restrict__ Gih,
    const float* __restrict__ hmid,
    u64* __restrict__ hb, float* __restrict__ hfinal) {
  const int b = blockIdx.x, t = threadIdx.x;
  const int w = t >> 6, lane = t & 63;
  const int quad = lane >> 4, r16 = lane & 15;

  // Preload W fragments: tile mt covers gates {2mt, 2mt+1}; A[m=r16][k=quad*8+j] per chunk.
  half8 afrag[2][8];
#pragma unroll
  for (int mt = 0; mt < 2; mt++) {
    int row = (2 * mt + (r16 >> 3)) * 1024 + b * 8 + (r16 & 7);
    const float* Wr = Whh + (size_t)row * 1024 + 256 * w + quad * 8;
#pragma unroll
    for (int ks = 0; ks < 8; ks++) {
      half8 v;
#pragma unroll
      for (int j = 0; j < 8; j++) v[j] = (_Float16)Wr[ks * 32 + j];
      afrag[mt][ks] = v;
    }
  }

  __shared__ __align__(16) u32 hsu[512];           // h as packed f16 pairs, wave-private quarters
  __shared__ __align__(16) float gpart[2][4][32];  // [buf][wave][tile*16+row]

  float cst = 0.0f;
  float4 Uvc = make_float4(0.f, 0.f, 0.f, 0.f);
  float4 Uvn = make_float4(0.f, 0.f, 0.f, 0.f);
  if (t < 8) {
    cst = hmid[b * 8 + t];  // c0 = h0 (fp32 exact)
    const u16* Ur = Gih + (size_t)0 * 4096 + (b * 8 + t);
    Uvc.x = b2f(Ur[0]); Uvc.y = b2f(Ur[1024]); Uvc.z = b2f(Ur[2048]); Uvc.w = b2f(Ur[3072]);
  }

  const int idx = 128 * w + 2 * lane;  // this lane's 2 words of the wave's quarter
  int n = 0;
  for (int s = 0; s < 128; s++) {
    for (int wI = 0; wI < 63; wI++, n++) {
      // prefetch Uv for step n+1 (consumed next iteration -> hides HBM miss)
      if (t < 8) {
        int nn = (n + 1 < 8064) ? n + 1 : 8063;
        const u16* Ur = Gih + (size_t)nn * 4096 + (b * 8 + t);
        Uvn.x = b2f(Ur[0]); Uvn.y = b2f(Ur[1024]); Uvn.z = b2f(Ur[2048]); Uvn.w = b2f(Ur[3072]);
      }
      // poll this wave's quarter of h_n (tight spin, relaxed agent atomics)
      const u64* p = hb + (size_t)(n & 1) * 512 + idx;
      const u32 tn = (u32)n;
      u64 v0, v1;
      for (;;) {
        v0 = aload(p + 0);
        v1 = aload(p + 1);
        if (((u32)(v0 >> 32) == tn) & ((u32)(v1 >> 32) == tn)) break;
      }
      hsu[idx] = (u32)v0;
      hsu[idx + 1] = (u32)v1;
      // matvec partials: 2 m-tiles x 8 chained MFMA over this wave's k-quarter
      f32x4 acc0 = {}, acc1 = {};
      const int kb = 128 * w;
#pragma unroll
      for (int ks = 0; ks < 8; ks++) {
        half8 bfrag = *(const half8*)&hsu[kb + 16 * ks + 4 * quad];
        acc0 = __builtin_amdgcn_mfma_f32_16x16x32_f16(afrag[0][ks], bfrag, acc0, 0, 0, 0);
        acc1 = __builtin_amdgcn_mfma_f32_16x16x32_f16(afrag[1][ks], bfrag, acc1, 0, 0, 0);
      }
      // C cols all identical; col 0 carriers (r16==0) write rows quad*4+reg
      if (r16 == 0) {
        *(f32x4*)&gpart[n & 1][w][4 * quad] = acc0;
        *(f32x4*)&gpart[n & 1][w][16 + 4 * quad] = acc1;
      }
      __syncthreads();
      if (t < 8) {
        float gi = 0.f, gf = 0.f, gg = 0.f, go = 0.f;
#pragma unroll
        for (int ww = 0; ww < 4; ww++) {
          gi += gpart[n & 1][ww][0 + t];
          gf += gpart[n & 1][ww][8 + t];
          gg += gpart[n & 1][ww][16 + t];
          go += gpart[n & 1][ww][24 + t];
        }
        gi += Uvc.x; gf += Uvc.y; gg += Uvc.z; go += Uvc.w;
        float iv = sigmoidf_(gi), fv = sigmoidf_(gf), gv = tanhf(gg), ov = sigmoidf_(go);
        cst = fv * cst + iv * gv;
        float h = ov * tanhf(cst);
        u32 hb16 = (u32)f2h(h);
        u32 other = (u32)__shfl_down((int)hb16, 1);
        if ((t & 1) == 0) {
          u64 word = ((u64)(u32)(n + 1) << 32) | (hb16 | (other << 16));
          __hip_atomic_store(&hb[(size_t)((n + 1) & 1) * 512 + b * 4 + (t >> 1)], word,
                             __ATOMIC_RELAXED, __HIP_MEMORY_SCOPE_AGENT);
        }
        if (wI == 62) hfinal[(size_t)s * 1024 + b * 8 + t] = h;
      }
      Uvc = Uvn;
    }
  }
}

// ---------------- row-wise log_softmax ----------------
__global__ __launch_bounds__(256) void k_lsm(const float* __restrict__ logits, float* __restrict__ out) {
  int s = blockIdx.x, t = threadIdx.x;
  const float* L = logits + (size_t)s * 1024;
  __shared__ float red[4], red2[4];
  float m = -1e30f;
  for (int i = t; i < 1024; i += 256) m = fmaxf(m, L[i]);
  for (int o = 1; o < 64; o <<= 1) m = fmaxf(m, __shfl_xor(m, o));
  if ((t & 63) == 0) red[t >> 6] = m;
  __syncthreads();
  m = fmaxf(fmaxf(red[0], red[1]), fmaxf(red[2], red[3]));
  float sum = 0.f;
  for (int i = t; i < 1024; i += 256) sum += expf(L[i] - m);
  for (int o = 1; o < 64; o <<= 1) sum += __shfl_xor(sum, o);
  if ((t & 63) == 0) red2[t >> 6] = sum;
  __syncthreads();
  sum = red2[0] + red2[1] + red2[2] + red2[3];
  float lse = m + logf(sum);
  for (int i = t; i < 1024; i += 256) out[(size_t)s * 1024 + i] = L[i] - lse;
}

extern "C" void kernel_launch(void* const* d_in, const int* in_sizes, int n_in,
                              void* d_out, int out_size, void* d_ws, size_t ws_size,
                              hipStream_t stream) {
  const float* x     = (const float*)d_in[0];
  const float* Wih_e = (const float*)d_in[1];
  const float* Whh_e = (const float*)d_in[2];
  const float* b_e   = (const float*)d_in[3];
  const float* Wm1   = (const float*)d_in[4];
  const float* bm1   = (const float*)d_in[5];
  const float* Wm2   = (const float*)d_in[6];
  const float* bm2   = (const float*)d_in[7];
  const float* Wih_d = (const float*)d_in[8];
  const float* Whh_d = (const float*)d_in[9];
  const float* b_d   = (const float*)d_in[10];
  const float* Wo    = (const float*)d_in[11];
  const float* bo    = (const float*)d_in[12];
  float* out = (float*)d_out;

  char* w = (char*)d_ws;
  size_t off = 0;
  auto alloc = [&](size_t bytes) { size_t r = off; off += (bytes + 255) & ~(size_t)255; return r; };
  u16* Chi = (u16*)(w + alloc((size_t)1024 * 1024 * 2));
  u16* Clo = (u16*)(w + alloc((size_t)1024 * 1024 * 2));
  u16* F1  = (u16*)(w + alloc((size_t)8064 * 1024 * 2));
  char* f2slot = w + alloc((size_t)8064 * 1024 * 2);   // Win_hi, later F2
  u16* WinHi = (u16*)f2slot;
  u16* F2    = (u16*)f2slot;
  u16* WinLo = (u16*)(w + alloc((size_t)8064 * 1024 * 2));
  char* gislot = w + alloc((size_t)8064 * 4096 * 2);   // Fgem (fp32 33MB), later Gih_d (bf16 66MB)
  float* Fgem = (float*)gislot;
  u16* Gih    = (u16*)gislot;
  u16* Gihe = (u16*)(w + alloc((size_t)8064 * 4096 * 2));  // encoder input projections (bf16)
  u16* Wihd  = (u16*)(w + alloc((size_t)4096 * 1024 * 2));
  u16* Wihe  = (u16*)(w + alloc((size_t)4096 * 1024 * 2));
  u16* Whhe  = (u16*)(w + alloc((size_t)4096 * 1024 * 2));
  u16* Wm1b = (u16*)(w + alloc((size_t)1024 * 1024 * 2));
  u16* Wm2b = (u16*)(w + alloc((size_t)1024 * 1024 * 2));
  u16* Wob  = (u16*)(w + alloc((size_t)1024 * 1024 * 2));
  u16* At   = (u16*)(w + alloc((size_t)128 * 1024 * 2));
  float* Ge = (float*)(w + alloc((size_t)128 * 4096 * 4));
  float* Ce = (float*)(w + alloc((size_t)128 * 1024 * 4));
  u16* Mid1 = (u16*)(w + alloc((size_t)128 * 1024 * 2));
  float* Hmid = (float*)(w + alloc((size_t)128 * 1024 * 4));
  u64* Hb = (u64*)(w + alloc((size_t)1024 * 8));
  float* Hfin = (float*)(w + alloc((size_t)128 * 1024 * 4));
  u16* Hfinb  = (u16*)(w + alloc((size_t)128 * 1024 * 2));
  float* Logit = (float*)(w + alloc((size_t)128 * 1024 * 4));
  (void)ws_size; (void)in_sizes; (void)n_in; (void)out_size;

  hipMemsetAsync(At, 0, (size_t)128 * 1024 * 2, stream);   // h=0 for encoder step 0
  hipMemsetAsync(Ce, 0, (size_t)128 * 1024 * 4, stream);

  // Fourier features: F = windows @ C, hi/lo split for ~fp32 accuracy
  k_cos<<<4096, 256, 0, stream>>>(Chi, Clo);
  k_win<<<8064, 256, 0, stream>>>(x, WinHi, WinLo);
  gemm_bt<0, false, false><<<dim3(16, 126), 256, 0, stream>>>(WinHi, 1024, Chi, 1024, Fgem, 1024, nullptr, 8064, 1024, 1024);
  gemm_bt<0, false, true><<<dim3(16, 126), 256, 0, stream>>>(WinHi, 1024, Clo, 1024, Fgem, 1024, nullptr, 8064, 1024, 1024);
  gemm_bt<0, false, true><<<dim3(16, 126), 256, 0, stream>>>(WinLo, 1024, Chi, 1024, Fgem, 1024, nullptr, 8064, 1024, 1024);
  k_f2bk<<<8064, 256, 0, stream>>>(Fgem, F1);        // F1 bf16, (w,s) order
  k_perm<<<4032, 256, 0, stream>>>(F1, F2);          // F2 bf16, (s,w) order

  // weight conversions
  k_f2bk<<<4096, 256, 0, stream>>>(Wih_d, Wihd);
  k_f2bk<<<4096, 256, 0, stream>>>(Wih_e, Wihe);
  k_f2bk<<<4096, 256, 0, stream>>>(Whh_e, Whhe);
  k_f2bk<<<1024, 256, 0, stream>>>(Wm1, Wm1b);
  k_f2bk<<<1024, 256, 0, stream>>>(Wm2, Wm2b);
  k_f2bk<<<1024, 256, 0, stream>>>(Wo, Wob);

  // batched input projections: decoder Gih = F2 @ Wih_d^T + b_d; encoder Gihe = F1 @ Wih_e^T + b_e
  gemm_bt<0, true, false><<<dim3(64, 126), 256, 0, stream>>>(F2, 1024, Wihd, 1024, Gih, 4096, b_d, 8064, 4096, 1024);
  gemm_bt<0, true, false><<<dim3(64, 126), 256, 0, stream>>>(F1, 1024, Wihe, 1024, Gihe, 4096, b_e, 8064, 4096, 1024);

  // encoder: 63 steps of gates = h @ Whh_e^T (+Gihe in cell), then cell
  for (int t = 0; t < 63; t++) {
    gemm_bt<0, false, false><<<dim3(64, 2), 256, 0, stream>>>(At, 1024, Whhe, 1024, Ge, 4096, nullptr, 128, 4096, 1024);
    k_cell_enc<<<512, 256, 0, stream>>>(Ge, Gihe, t, Ce, At);
  }

  // mid MLP: tanh(relu(h_enc @ Wm1^T + bm1) @ Wm2^T + bm2)
  gemm_bt<1, true, false><<<dim3(16, 2), 256, 0, stream>>>(At, 1024, Wm1b, 1024, Mid1, 1024, bm1, 128, 1024, 1024);
  gemm_bt<2, false, false><<<dim3(16, 2), 256, 0, stream>>>(Mid1, 1024, Wm2b, 1024, Hmid, 1024, bm2, 128, 1024, 1024);

  // decoder
  k_initdec<<<4, 256, 0, stream>>>(Hmid, Hb);
  dec_persist<<<128, 256, 0, stream>>>(Whh_d, Gih, Hmid, Hb, Hfin);

  // output head: log_softmax(h_final @ Wo^T + bo)
  k_f2bk<<<128, 256, 0, stream>>>(Hfin, Hfinb);
  gemm_bt<0, false, false><<<dim3(16, 2), 256, 0, stream>>>(Hfinb, 1024, Wob, 1024, Logit, 1024, bo, 128, 1024, 1024);
  k_lsm<<<128, 256, 0, stream>>>(Logit, out);
}

// Round 4
// 18167.461 us; speedup vs baseline: 3.3672x; 1.0575x over previous
//
#include <hip/hip_runtime.h>

typedef unsigned short u16;
typedef unsigned u32;
typedef unsigned long long u64;
typedef __bf16 bf16x8 __attribute__((ext_vector_type(8)));
typedef _Float16 half8 __attribute__((ext_vector_type(8)));
typedef float f32x4 __attribute__((ext_vector_type(4)));

__device__ __forceinline__ u16 f2b(float f) {
  unsigned u = __builtin_bit_cast(unsigned, f);
  u = (u + 0x7FFFu + ((u >> 16) & 1u)) >> 16;
  return (u16)u;
}
__device__ __forceinline__ float b2f(u16 h) {
  return __builtin_bit_cast(float, ((unsigned)h) << 16);
}
__device__ __forceinline__ u16 f2h(float f) {
  _Float16 h = (_Float16)f;
  return __builtin_bit_cast(unsigned short, h);
}
__device__ __forceinline__ float sigmoidf_(float x) { return 1.0f / (1.0f + expf(-x)); }
__device__ __forceinline__ float fsig(float x) {
  x = fminf(fmaxf(x, -30.f), 30.f);
  return 1.0f / (1.0f + __expf(-x));
}
__device__ __forceinline__ float ftanh_(float x) {
  x = fminf(fmaxf(x, -15.f), 15.f);
  float e = __expf(2.0f * x);
  return (e - 1.0f) / (e + 1.0f);
}
__device__ __forceinline__ u64 aload(const u64* p) {
  return __hip_atomic_load(p, __ATOMIC_RELAXED, __HIP_MEMORY_SCOPE_AGENT);
}

// ---------------- generic bf16 MFMA GEMM: C[M,N] = A[M,K] @ B[N,K]^T (+C) (+bias) ----------------
// SLAB: write output in decoder per-block slab layout GihS[bb][m][q*32+jj] (bb=col/32 block)
template <int EPI, bool OUTBF, bool ACC, bool SLAB = false>
__global__ __launch_bounds__(256) void gemm_bt(
    const u16* __restrict__ A, int lda,
    const u16* __restrict__ B, int ldb,
    void* __restrict__ Cout, int ldc,
    const float* __restrict__ bias,
    int M, int N, int K) {
  __shared__ __align__(16) u16 As[64 * 40];
  __shared__ __align__(16) u16 Bs[64 * 40];
  const int t = threadIdx.x;
  const int n0 = blockIdx.x * 64, m0 = blockIdx.y * 64;
  const int wave = t >> 6, lane = t & 63;
  const int wm = (wave >> 1) * 32, wn = (wave & 1) * 32;
  const int quad = lane >> 4, r16 = lane & 15;
  const int srow = t >> 2, scol = (t & 3) * 8;
  f32x4 acc[2][2] = {};
  const u16* ap = A + (size_t)(m0 + srow) * lda + scol;
  const u16* bp = B + (size_t)(n0 + srow) * ldb + scol;
  for (int k0 = 0; k0 < K; k0 += 32) {
    uint4 av = *(const uint4*)(ap + k0);
    uint4 bv = *(const uint4*)(bp + k0);
    __syncthreads();
    *(uint4*)&As[srow * 40 + scol] = av;
    *(uint4*)&Bs[srow * 40 + scol] = bv;
    __syncthreads();
    bf16x8 a0 = *(const bf16x8*)&As[(wm + r16) * 40 + quad * 8];
    bf16x8 a1 = *(const bf16x8*)&As[(wm + 16 + r16) * 40 + quad * 8];
    bf16x8 b0 = *(const bf16x8*)&Bs[(wn + r16) * 40 + quad * 8];
    bf16x8 b1 = *(const bf16x8*)&Bs[(wn + 16 + r16) * 40 + quad * 8];
    acc[0][0] = __builtin_amdgcn_mfma_f32_16x16x32_bf16(a0, b0, acc[0][0], 0, 0, 0);
    acc[0][1] = __builtin_amdgcn_mfma_f32_16x16x32_bf16(a0, b1, acc[0][1], 0, 0, 0);
    acc[1][0] = __builtin_amdgcn_mfma_f32_16x16x32_bf16(a1, b0, acc[1][0], 0, 0, 0);
    acc[1][1] = __builtin_amdgcn_mfma_f32_16x16x32_bf16(a1, b1, acc[1][1], 0, 0, 0);
  }
  for (int mi = 0; mi < 2; mi++)
    for (int ni = 0; ni < 2; ni++)
      for (int r = 0; r < 4; r++) {
        int gm = m0 + wm + mi * 16 + quad * 4 + r;
        int gn = n0 + wn + ni * 16 + r16;
        float v = acc[mi][ni][r];
        size_t idx;
        if (SLAB) {
          int q = gn >> 10, bb = (gn >> 5) & 31, jj = gn & 31;
          idx = ((size_t)bb * 8064 + gm) * 128 + q * 32 + jj;
        } else {
          idx = (size_t)gm * ldc + gn;
        }
        if (ACC) v += ((float*)Cout)[idx];
        if (bias) v += bias[gn];
        if (EPI == 1) v = fmaxf(v, 0.0f);
        if (EPI == 2) v = tanhf(v);
        if (OUTBF) ((u16*)Cout)[idx] = f2b(v);
        else ((float*)Cout)[idx] = v;
      }
}

// ---------------- cosine matrix, hi/lo bf16 split ----------------
__global__ __launch_bounds__(256) void k_cos(u16* __restrict__ Chi, u16* __restrict__ Clo) {
  int gid = blockIdx.x * 256 + threadIdx.x;
  int k = gid >> 10, n = gid & 1023;
  int m = (k * n) & 1023;
  float c = cospif((float)m * (1.0f / 512.0f));
  u16 hi = f2b(c);
  Chi[gid] = hi;
  Clo[gid] = f2b(c - b2f(hi));
}

// ---------------- window extraction (w,s order), hi/lo bf16 split ----------------
__global__ __launch_bounds__(256) void k_win(const float* __restrict__ x,
                                             u16* __restrict__ Whi, u16* __restrict__ Wlo) {
  int gid = blockIdx.x * 256 + threadIdx.x;
  int e = gid * 4;
  int r = e >> 10, n = e & 1023;
  int wI = r >> 7, s = r & 127;
  const float* src = x + (size_t)s * 32768 + wI * 512 + n;
  float4 v = *(const float4*)src;
  float vv[4] = {v.x, v.y, v.z, v.w};
#pragma unroll
  for (int i = 0; i < 4; i++) {
    u16 hi = f2b(vv[i]);
    Whi[e + i] = hi;
    Wlo[e + i] = f2b(vv[i] - b2f(hi));
  }
}

// ---------------- fp32 -> bf16 ----------------
__global__ __launch_bounds__(256) void k_f2bk(const float* __restrict__ src, u16* __restrict__ dst) {
  int gid = blockIdx.x * 256 + threadIdx.x;
  int i = gid * 4;
  float4 v = *(const float4*)(src + i);
  dst[i] = f2b(v.x); dst[i + 1] = f2b(v.y); dst[i + 2] = f2b(v.z); dst[i + 3] = f2b(v.w);
}

// ---------------- permute F (w,s)->(s,w) order ----------------
__global__ __launch_bounds__(256) void k_perm(const u16* __restrict__ F1, u16* __restrict__ F2) {
  int gid = blockIdx.x * 256 + threadIdx.x;
  int ro = gid >> 7, n8 = (gid & 127) * 8;
  int s = ro / 63, wI = ro % 63;
  *(uint4*)&F2[(size_t)ro * 1024 + n8] = *(const uint4*)&F1[(size_t)(wI * 128 + s) * 1024 + n8];
}

// ---------------- encoder LSTM cell (adds precomputed input projection) ----------------
__global__ __launch_bounds__(256) void k_cell_enc(const float* __restrict__ g,
                                                  const u16* __restrict__ gihe, int t0,
                                                  float* __restrict__ c_e,
                                                  u16* __restrict__ At) {
  int gid = blockIdx.x * 256 + threadIdx.x;  // 128*1024
  int s = gid >> 10, j = gid & 1023;
  const float* gr = g + (size_t)s * 4096;
  const u16* er = gihe + (size_t)(t0 * 128 + s) * 4096;
  float iv = sigmoidf_(gr[j] + b2f(er[j]));
  float fv = sigmoidf_(gr[j + 1024] + b2f(er[j + 1024]));
  float gv = tanhf(gr[j + 2048] + b2f(er[j + 2048]));
  float ov = sigmoidf_(gr[j + 3072] + b2f(er[j + 3072]));
  float c = fv * c_e[gid] + iv * gv;
  c_e[gid] = c;
  At[(size_t)s * 1024 + j] = f2b(ov * tanhf(c));
}

// ---------------- decoder init: h words = {tag | 2 x f16}, both buffers ----------------
__global__ void k_initdec(const float* __restrict__ hmid, u64* __restrict__ hb) {
  int gid = blockIdx.x * blockDim.x + threadIdx.x;  // 1024
  if (gid < 512) {
    u32 lo = (u32)f2h(hmid[2 * gid]) | ((u32)f2h(hmid[2 * gid + 1]) << 16);
    hb[gid] = (u64)lo;                              // buffer 0: h_0, tag 0
  } else if (gid < 1024) {
    hb[gid] = 0xFFFFFFFF00000000ull;                // buffer 1: sentinel tag
  }
}

// ---------------- persistent decoder: 32 blocks, W fully in VGPRs, slab-staged Gih ----------------
// 32 blocks x 256 threads. Block b owns outputs j = b*32..b*32+31 (128 gate-rows of Whh_d
// as f16 MFMA A-fragments: 256 VGPR/thread). Wave w covers k-quarter 256w..256w+256.
// h exchanged as 512 u64 {tag|2xf16} words, relaxed agent atomics; each thread polls one
// dwordx4 (2 words). Gih pre-permuted to per-block slabs, LDS double-buffered 16 steps.
__global__ __launch_bounds__(256, 1) void dec_persist(
    const float* __restrict__ Whh, const u16* __restrict__ GihS,
    const float* __restrict__ hmid,
    u64* __restrict__ hb, float* __restrict__ hfinal) {
  const int b = blockIdx.x, t = threadIdx.x;
  const int w = t >> 6, lane = t & 63;
  const int quad = lane >> 4, r16 = lane & 15;

  // A-fragments: tile mt covers local gate-rows mt*16..mt*16+15 (local row = gate*32 + jj)
  half8 afrag[8][8];
#pragma unroll
  for (int mt = 0; mt < 8; mt++) {
    int lr = mt * 16 + r16;
    int q = lr >> 5, jj = lr & 31;
    const float* Wr = Whh + (size_t)(q * 1024 + b * 32 + jj) * 1024 + 256 * w + quad * 8;
#pragma unroll
    for (int ks = 0; ks < 8; ks++) {
      half8 v;
#pragma unroll
      for (int j = 0; j < 8; j++) v[j] = (_Float16)Wr[ks * 32 + j];
      afrag[mt][ks] = v;
    }
  }

  __shared__ __align__(16) u32 hsu[512];        // h as f16 pairs (wave-private quarters)
  __shared__ float gpart[2][4][128];            // [buf][wave][local gate-row]
  __shared__ __align__(16) u16 uslab[2][2048];  // [buf][step(16) x 128 gates]

  // stage slab 0 (steps 0..15); consumed after in-loop barriers
  {
    uint4 g0 = *(const uint4*)(GihS + (size_t)b * 8064 * 128 + t * 8);
    *(uint4*)&uslab[0][t * 8] = g0;
  }
  float cst = (t < 32) ? hmid[b * 32 + t] : 0.0f;  // c0 = h0 (fp32 exact)

  int n = 0;
  for (int s = 0; s < 128; s++) {
    for (int wI = 0; wI < 63; wI++, n++) {
      // poll own 2 words (one dwordx4) of h_n
      const u32 tn = (u32)n;
      const u64* p = hb + (size_t)(n & 1) * 512 + 2 * t;
      u64 v0, v1;
      for (;;) {
        v0 = aload(p);
        v1 = aload(p + 1);
        if (((u32)(v0 >> 32) == tn) & ((u32)(v1 >> 32) == tn)) break;
      }
      ((u64*)hsu)[t] = (v0 & 0xFFFFFFFFull) | (v1 << 32);  // h[4t..4t+3]

      // issue next-slab prefetch under the MFMA shadow (once per 16 steps)
      const bool slabload = (n & 15) == 0;
      uint4 gsv;
      if (slabload) {
        int nn = (n + 16 <= 8048) ? n + 16 : 8048;
        gsv = *(const uint4*)(GihS + ((size_t)b * 8064 + nn) * 128 + t * 8);
      }

      // matvec partials: 8 m-tiles x 8 k-steps over this wave's quarter
      f32x4 acc[8];
#pragma unroll
      for (int mt = 0; mt < 8; mt++) acc[mt] = (f32x4){0.f, 0.f, 0.f, 0.f};
      const int kb = 128 * w;
#pragma unroll
      for (int ks = 0; ks < 8; ks++) {
        half8 bfrag = *(const half8*)&hsu[kb + 16 * ks + 4 * quad];
#pragma unroll
        for (int mt = 0; mt < 8; mt++)
          acc[mt] = __builtin_amdgcn_mfma_f32_16x16x32_f16(afrag[mt][ks], bfrag, acc[mt], 0, 0, 0);
      }
      if (r16 == 0) {  // col 0 carriers: rows quad*4+reg of each tile
#pragma unroll
        for (int mt = 0; mt < 8; mt++)
          *(f32x4*)&gpart[n & 1][w][mt * 16 + 4 * quad] = acc[mt];
      }
      __syncthreads();
      // slab write AFTER barrier: prior-step readers of the other buffer are provably done
      if (slabload) *(uint4*)&uslab[((n >> 4) + 1) & 1][t * 8] = gsv;
      if (t < 32) {
        const int pb = n & 1, sb = (n >> 4) & 1, so = (n & 15) * 128;
        float gi = gpart[pb][0][t] + gpart[pb][1][t] + gpart[pb][2][t] + gpart[pb][3][t];
        float gf = gpart[pb][0][32 + t] + gpart[pb][1][32 + t] + gpart[pb][2][32 + t] + gpart[pb][3][32 + t];
        float gg = gpart[pb][0][64 + t] + gpart[pb][1][64 + t] + gpart[pb][2][64 + t] + gpart[pb][3][64 + t];
        float go = gpart[pb][0][96 + t] + gpart[pb][1][96 + t] + gpart[pb][2][96 + t] + gpart[pb][3][96 + t];
        gi += b2f(uslab[sb][so + t]);
        gf += b2f(uslab[sb][so + 32 + t]);
        gg += b2f(uslab[sb][so + 64 + t]);
        go += b2f(uslab[sb][so + 96 + t]);
        float iv = fsig(gi), fv = fsig(gf), gv = ftanh_(gg), ov = fsig(go);
        cst = fv * cst + iv * gv;
        float h = ov * ftanh_(cst);
        u32 h16 = (u32)f2h(h);
        u32 oth = (u32)__shfl_down((int)h16, 1);
        if ((t & 1) == 0) {
          u64 word = ((u64)(u32)(n + 1) << 32) | (h16 | (oth << 16));
          __hip_atomic_store(&hb[(size_t)((n + 1) & 1) * 512 + b * 16 + (t >> 1)], word,
                             __ATOMIC_RELAXED, __HIP_MEMORY_SCOPE_AGENT);
        }
        if (wI == 62) hfinal[(size_t)s * 1024 + b * 32 + t] = h;
      }
    }
  }
}

// ---------------- row-wise log_softmax ----------------
__global__ __launch_bounds__(256) void k_lsm(const float* __restrict__ logits, float* __restrict__ out) {
  int s = blockIdx.x, t = threadIdx.x;
  const float* L = logits + (size_t)s * 1024;
  __shared__ float red[4], red2[4];
  float m = -1e30f;
  for (int i = t; i < 1024; i += 256) m = fmaxf(m, L[i]);
  for (int o = 1; o < 64; o <<= 1) m = fmaxf(m, __shfl_xor(m, o));
  if ((t & 63) == 0) red[t >> 6] = m;
  __syncthreads();
  m = fmaxf(fmaxf(red[0], red[1]), fmaxf(red[2], red[3]));
  float sum = 0.f;
  for (int i = t; i < 1024; i += 256) sum += expf(L[i] - m);
  for (int o = 1; o < 64; o <<= 1) sum += __shfl_xor(sum, o);
  if ((t & 63) == 0) red2[t >> 6] = sum;
  __syncthreads();
  sum = red2[0] + red2[1] + red2[2] + red2[3];
  float lse = m + logf(sum);
  for (int i = t; i < 1024; i += 256) out[(size_t)s * 1024 + i] = L[i] - lse;
}

extern "C" void kernel_launch(void* const* d_in, const int* in_sizes, int n_in,
                              void* d_out, int out_size, void* d_ws, size_t ws_size,
                              hipStream_t stream) {
  const float* x     = (const float*)d_in[0];
  const float* Wih_e = (const float*)d_in[1];
  const float* Whh_e = (const float*)d_in[2];
  const float* b_e   = (const float*)d_in[3];
  const float* Wm1   = (const float*)d_in[4];
  const float* bm1   = (const float*)d_in[5];
  const float* Wm2   = (const float*)d_in[6];
  const float* bm2   = (const float*)d_in[7];
  const float* Wih_d = (const float*)d_in[8];
  const float* Whh_d = (const float*)d_in[9];
  const float* b_d   = (const float*)d_in[10];
  const float* Wo    = (const float*)d_in[11];
  const float* bo    = (const float*)d_in[12];
  float* out = (float*)d_out;

  char* w = (char*)d_ws;
  size_t off = 0;
  auto alloc = [&](size_t bytes) { size_t r = off; off += (bytes + 255) & ~(size_t)255; return r; };
  u16* Chi = (u16*)(w + alloc((size_t)1024 * 1024 * 2));
  u16* Clo = (u16*)(w + alloc((size_t)1024 * 1024 * 2));
  u16* F1  = (u16*)(w + alloc((size_t)8064 * 1024 * 2));
  char* f2slot = w + alloc((size_t)8064 * 1024 * 2);   // Win_hi, later F2
  u16* WinHi = (u16*)f2slot;
  u16* F2    = (u16*)f2slot;
  u16* WinLo = (u16*)(w + alloc((size_t)8064 * 1024 * 2));
  char* gislot = w + alloc((size_t)8064 * 4096 * 2);   // Fgem (fp32 33MB), later GihS (bf16 66MB, slab)
  float* Fgem = (float*)gislot;
  u16* GihS   = (u16*)gislot;
  u16* Gihe = (u16*)(w + alloc((size_t)8064 * 4096 * 2));  // encoder input projections (bf16)
  u16* Wihd  = (u16*)(w + alloc((size_t)4096 * 1024 * 2));
  u16* Wihe  = (u16*)(w + alloc((size_t)4096 * 1024 * 2));
  u16* Whhe  = (u16*)(w + alloc((size_t)4096 * 1024 * 2));
  u16* Wm1b = (u16*)(w + alloc((size_t)1024 * 1024 * 2));
  u16* Wm2b = (u16*)(w + alloc((size_t)1024 * 1024 * 2));
  u16* Wob  = (u16*)(w + alloc((size_t)1024 * 1024 * 2));
  u16* At   = (u16*)(w + alloc((size_t)128 * 1024 * 2));
  float* Ge = (float*)(w + alloc((size_t)128 * 4096 * 4));
  float* Ce = (float*)(w + alloc((size_t)128 * 1024 * 4));
  u16* Mid1 = (u16*)(w + alloc((size_t)128 * 1024 * 2));
  float* Hmid = (float*)(w + alloc((size_t)128 * 1024 * 4));
  u64* Hb = (u64*)(w + alloc((size_t)1024 * 8));
  float* Hfin = (float*)(w + alloc((size_t)128 * 1024 * 4));
  u16* Hfinb  = (u16*)(w + alloc((size_t)128 * 1024 * 2));
  float* Logit = (float*)(w + alloc((size_t)128 * 1024 * 4));
  (void)ws_size; (void)in_sizes; (void)n_in; (void)out_size;

  hipMemsetAsync(At, 0, (size_t)128 * 1024 * 2, stream);   // h=0 for encoder step 0
  hipMemsetAsync(Ce, 0, (size_t)128 * 1024 * 4, stream);

  // Fourier features: F = windows @ C, hi/lo split for ~fp32 accuracy
  k_cos<<<4096, 256, 0, stream>>>(Chi, Clo);
  k_win<<<8064, 256, 0, stream>>>(x, WinHi, WinLo);
  gemm_bt<0, false, false><<<dim3(16, 126), 256, 0, stream>>>(WinHi, 1024, Chi, 1024, Fgem, 1024, nullptr, 8064, 1024, 1024);
  gemm_bt<0, false, true><<<dim3(16, 126), 256, 0, stream>>>(WinHi, 1024, Clo, 1024, Fgem, 1024, nullptr, 8064, 1024, 1024);
  gemm_bt<0, false, true><<<dim3(16, 126), 256, 0, stream>>>(WinLo, 1024, Chi, 1024, Fgem, 1024, nullptr, 8064, 1024, 1024);
  k_f2bk<<<8064, 256, 0, stream>>>(Fgem, F1);        // F1 bf16, (w,s) order
  k_perm<<<4032, 256, 0, stream>>>(F1, F2);          // F2 bf16, (s,w) order

  // weight conversions
  k_f2bk<<<4096, 256, 0, stream>>>(Wih_d, Wihd);
  k_f2bk<<<4096, 256, 0, stream>>>(Wih_e, Wihe);
  k_f2bk<<<4096, 256, 0, stream>>>(Whh_e, Whhe);
  k_f2bk<<<1024, 256, 0, stream>>>(Wm1, Wm1b);
  k_f2bk<<<1024, 256, 0, stream>>>(Wm2, Wm2b);
  k_f2bk<<<1024, 256, 0, stream>>>(Wo, Wob);

  // batched input projections: decoder (slab layout) + encoder
  gemm_bt<0, true, false, true><<<dim3(64, 126), 256, 0, stream>>>(F2, 1024, Wihd, 1024, GihS, 128, b_d, 8064, 4096, 1024);
  gemm_bt<0, true, false><<<dim3(64, 126), 256, 0, stream>>>(F1, 1024, Wihe, 1024, Gihe, 4096, b_e, 8064, 4096, 1024);

  // encoder: 63 steps of gates = h @ Whh_e^T (+Gihe in cell), then cell
  for (int t = 0; t < 63; t++) {
    gemm_bt<0, false, false><<<dim3(64, 2), 256, 0, stream>>>(At, 1024, Whhe, 1024, Ge, 4096, nullptr, 128, 4096, 1024);
    k_cell_enc<<<512, 256, 0, stream>>>(Ge, Gihe, t, Ce, At);
  }

  // mid MLP: tanh(relu(h_enc @ Wm1^T + bm1) @ Wm2^T + bm2)
  gemm_bt<1, true, false><<<dim3(16, 2), 256, 0, stream>>>(At, 1024, Wm1b, 1024, Mid1, 1024, bm1, 128, 1024, 1024);
  gemm_bt<2, false, false><<<dim3(16, 2), 256, 0, stream>>>(Mid1, 1024, Wm2b, 1024, Hmid, 1024, bm2, 128, 1024, 1024);

  // decoder
  k_initdec<<<4, 256, 0, stream>>>(Hmid, Hb);
  dec_persist<<<32, 256, 0, stream>>>(Whh_d, GihS, Hmid, Hb, Hfin);

  // output head: log_softmax(h_final @ Wo^T + bo)
  k_f2bk<<<128, 256, 0, stream>>>(Hfin, Hfinb);
  gemm_bt<0, false, false><<<dim3(16, 2), 256, 0, stream>>>(Hfinb, 1024, Wob, 1024, Logit, 1024, bo, 128, 1024, 1024);
  k_lsm<<<128, 256, 0, stream>>>(Logit, out);
}

// Round 6
// 17413.550 us; speedup vs baseline: 3.5130x; 1.0433x over previous
//
#include <hip/hip_runtime.h>

typedef unsigned short u16;
typedef unsigned u32;
typedef unsigned long long u64;
typedef __bf16 bf16x8 __attribute__((ext_vector_type(8)));
typedef _Float16 half8 __attribute__((ext_vector_type(8)));
typedef float f32x4 __attribute__((ext_vector_type(4)));
typedef unsigned uint4v __attribute__((ext_vector_type(4)));
typedef unsigned uint2v __attribute__((ext_vector_type(2)));

__device__ __forceinline__ u16 f2b(float f) {
  unsigned u = __builtin_bit_cast(unsigned, f);
  u = (u + 0x7FFFu + ((u >> 16) & 1u)) >> 16;
  return (u16)u;
}
__device__ __forceinline__ float b2f(u16 h) {
  return __builtin_bit_cast(float, ((unsigned)h) << 16);
}
__device__ __forceinline__ u16 f2h(float f) {
  _Float16 h = (_Float16)f;
  return __builtin_bit_cast(unsigned short, h);
}
__device__ __forceinline__ float sigmoidf_(float x) { return 1.0f / (1.0f + expf(-x)); }
__device__ __forceinline__ float fsig(float x) {
  x = fminf(fmaxf(x, -30.f), 30.f);
  return 1.0f / (1.0f + __expf(-x));
}
__device__ __forceinline__ float ftanh_(float x) {
  x = fminf(fmaxf(x, -15.f), 15.f);
  float e = __expf(2.0f * x);
  return (e - 1.0f) / (e + 1.0f);
}
__device__ __forceinline__ u64 aload(const u64* p) {
  return __hip_atomic_load(p, __ATOMIC_RELAXED, __HIP_MEMORY_SCOPE_AGENT);
}

// L2-coherent (same-XCD only!) exchange primitives: sc0 = miss L1, served by the XCD's L2.
// Correctness gated at runtime by the probe/verdict handshake below — never trusted blindly.
__device__ __forceinline__ void l2_poll2(const u64* p, u64& a, u64& b) {
  uint4v r;
  asm volatile("global_load_dwordx4 %0, %1, off sc0\n\ts_waitcnt vmcnt(0)"
               : "=&v"(r) : "v"(p) : "memory");
  a = ((u64)r.y << 32) | (u64)r.x;
  b = ((u64)r.w << 32) | (u64)r.z;
}
__device__ __forceinline__ u64 l2_load1(const u64* p) {
  uint2v r;
  asm volatile("global_load_dwordx2 %0, %1, off sc0\n\ts_waitcnt vmcnt(0)"
               : "=&v"(r) : "v"(p) : "memory");
  return ((u64)r.y << 32) | (u64)r.x;
}
__device__ __forceinline__ void l2_store(u64* p, u64 v) {
  asm volatile("global_store_dwordx2 %0, %1, off sc0" :: "v"(p), "v"(v) : "memory");
}

// ---------------- generic bf16 MFMA GEMM: C[M,N] = A[M,K] @ B[N,K]^T (+C) (+bias) ----------------
// SLAB: write output in decoder per-block slab layout GihS[bb][m][q*32+jj] (bb=col/32 block)
template <int EPI, bool OUTBF, bool ACC, bool SLAB = false>
__global__ __launch_bounds__(256) void gemm_bt(
    const u16* __restrict__ A, int lda,
    const u16* __restrict__ B, int ldb,
    void* __restrict__ Cout, int ldc,
    const float* __restrict__ bias,
    int M, int N, int K) {
  __shared__ __align__(16) u16 As[64 * 40];
  __shared__ __align__(16) u16 Bs[64 * 40];
  const int t = threadIdx.x;
  const int n0 = blockIdx.x * 64, m0 = blockIdx.y * 64;
  const int wave = t >> 6, lane = t & 63;
  const int wm = (wave >> 1) * 32, wn = (wave & 1) * 32;
  const int quad = lane >> 4, r16 = lane & 15;
  const int srow = t >> 2, scol = (t & 3) * 8;
  f32x4 acc[2][2] = {};
  const u16* ap = A + (size_t)(m0 + srow) * lda + scol;
  const u16* bp = B + (size_t)(n0 + srow) * ldb + scol;
  for (int k0 = 0; k0 < K; k0 += 32) {
    uint4 av = *(const uint4*)(ap + k0);
    uint4 bv = *(const uint4*)(bp + k0);
    __syncthreads();
    *(uint4*)&As[srow * 40 + scol] = av;
    *(uint4*)&Bs[srow * 40 + scol] = bv;
    __syncthreads();
    bf16x8 a0 = *(const bf16x8*)&As[(wm + r16) * 40 + quad * 8];
    bf16x8 a1 = *(const bf16x8*)&As[(wm + 16 + r16) * 40 + quad * 8];
    bf16x8 b0 = *(const bf16x8*)&Bs[(wn + r16) * 40 + quad * 8];
    bf16x8 b1 = *(const bf16x8*)&Bs[(wn + 16 + r16) * 40 + quad * 8];
    acc[0][0] = __builtin_amdgcn_mfma_f32_16x16x32_bf16(a0, b0, acc[0][0], 0, 0, 0);
    acc[0][1] = __builtin_amdgcn_mfma_f32_16x16x32_bf16(a0, b1, acc[0][1], 0, 0, 0);
    acc[1][0] = __builtin_amdgcn_mfma_f32_16x16x32_bf16(a1, b0, acc[1][0], 0, 0, 0);
    acc[1][1] = __builtin_amdgcn_mfma_f32_16x16x32_bf16(a1, b1, acc[1][1], 0, 0, 0);
  }
  for (int mi = 0; mi < 2; mi++)
    for (int ni = 0; ni < 2; ni++)
      for (int r = 0; r < 4; r++) {
        int gm = m0 + wm + mi * 16 + quad * 4 + r;
        int gn = n0 + wn + ni * 16 + r16;
        float v = acc[mi][ni][r];
        size_t idx;
        if (SLAB) {
          int q = gn >> 10, bb = (gn >> 5) & 31, jj = gn & 31;
          idx = ((size_t)bb * 8064 + gm) * 128 + q * 32 + jj;
        } else {
          idx = (size_t)gm * ldc + gn;
        }
        if (ACC) v += ((float*)Cout)[idx];
        if (bias) v += bias[gn];
        if (EPI == 1) v = fmaxf(v, 0.0f);
        if (EPI == 2) v = tanhf(v);
        if (OUTBF) ((u16*)Cout)[idx] = f2b(v);
        else ((float*)Cout)[idx] = v;
      }
}

// ---------------- cosine matrix, hi/lo bf16 split ----------------
__global__ __launch_bounds__(256) void k_cos(u16* __restrict__ Chi, u16* __restrict__ Clo) {
  int gid = blockIdx.x * 256 + threadIdx.x;
  int k = gid >> 10, n = gid & 1023;
  int m = (k * n) & 1023;
  float c = cospif((float)m * (1.0f / 512.0f));
  u16 hi = f2b(c);
  Chi[gid] = hi;
  Clo[gid] = f2b(c - b2f(hi));
}

// ---------------- window extraction (w,s order), hi/lo bf16 split ----------------
__global__ __launch_bounds__(256) void k_win(const float* __restrict__ x,
                                             u16* __restrict__ Whi, u16* __restrict__ Wlo) {
  int gid = blockIdx.x * 256 + threadIdx.x;
  int e = gid * 4;
  int r = e >> 10, n = e & 1023;
  int wI = r >> 7, s = r & 127;
  const float* src = x + (size_t)s * 32768 + wI * 512 + n;
  float4 v = *(const float4*)src;
  float vv[4] = {v.x, v.y, v.z, v.w};
#pragma unroll
  for (int i = 0; i < 4; i++) {
    u16 hi = f2b(vv[i]);
    Whi[e + i] = hi;
    Wlo[e + i] = f2b(vv[i] - b2f(hi));
  }
}

// ---------------- fp32 -> bf16 ----------------
__global__ __launch_bounds__(256) void k_f2bk(const float* __restrict__ src, u16* __restrict__ dst) {
  int gid = blockIdx.x * 256 + threadIdx.x;
  int i = gid * 4;
  float4 v = *(const float4*)(src + i);
  dst[i] = f2b(v.x); dst[i + 1] = f2b(v.y); dst[i + 2] = f2b(v.z); dst[i + 3] = f2b(v.w);
}

// ---------------- permute F (w,s)->(s,w) order ----------------
__global__ __launch_bounds__(256) void k_perm(const u16* __restrict__ F1, u16* __restrict__ F2) {
  int gid = blockIdx.x * 256 + threadIdx.x;
  int ro = gid >> 7, n8 = (gid & 127) * 8;
  int s = ro / 63, wI = ro % 63;
  *(uint4*)&F2[(size_t)ro * 1024 + n8] = *(const uint4*)&F1[(size_t)(wI * 128 + s) * 1024 + n8];
}

// ---------------- encoder LSTM cell (adds precomputed input projection) ----------------
__global__ __launch_bounds__(256) void k_cell_enc(const float* __restrict__ g,
                                                  const u16* __restrict__ gihe, int t0,
                                                  float* __restrict__ c_e,
                                                  u16* __restrict__ At) {
  int gid = blockIdx.x * 256 + threadIdx.x;  // 128*1024
  int s = gid >> 10, j = gid & 1023;
  const float* gr = g + (size_t)s * 4096;
  const u16* er = gihe + (size_t)(t0 * 128 + s) * 4096;
  float iv = sigmoidf_(gr[j] + b2f(er[j]));
  float fv = sigmoidf_(gr[j + 1024] + b2f(er[j + 1024]));
  float gv = tanhf(gr[j + 2048] + b2f(er[j + 2048]));
  float ov = sigmoidf_(gr[j + 3072] + b2f(er[j + 3072]));
  float c = fv * c_e[gid] + iv * gv;
  c_e[gid] = c;
  At[(size_t)s * 1024 + j] = f2b(ov * tanhf(c));
}

// ---------------- decoder init: h buffers, election ctrl, probe/verdict ----------------
__global__ void k_initdec(const float* __restrict__ hmid, u64* __restrict__ hb,
                          int* __restrict__ ctrl, u64* __restrict__ probe,
                          u32* __restrict__ verdict) {
  int gid = blockIdx.x * blockDim.x + threadIdx.x;  // 1024
  if (gid < 512) {
    u32 lo = (u32)f2h(hmid[2 * gid]) | ((u32)f2h(hmid[2 * gid + 1]) << 16);
    hb[gid] = (u64)lo;                              // buffer 0: h_0, tag 0
  } else if (gid < 1024) {
    hb[gid] = 0xFFFFFFFF00000000ull;                // buffer 1: sentinel tag
  }
  if (gid < 9) ctrl[gid] = (gid == 8) ? -1 : 0;     // ctrl[0..7]: per-XCD tickets; ctrl[8]: winner
  if (gid >= 16 && gid < 48) probe[gid - 16] = 0ull;
  if (gid >= 48 && gid < 80) verdict[gid - 48] = 0u;
}

// ---------------- persistent decoder: single-XCD fast path + verified fallback ----------------
// 256 blocks launched (all co-resident at <=2 blocks/CU). Election: per-XCD device-scope
// tickets; first XCD to collect 32 blocks wins (terminates by pigeonhole regardless of what
// XCC_ID returns). The 32 winners then PROBE the sc0/L2 channel (8 bounded rounds of
// all-pairs visibility), publish verdicts at agent scope (proven-reliable channel), and
// unanimously pick: fast sc0/L2 exchange, or the R4 agent-scope exchange as fallback.
// Worker slot b owns outputs j = b*32..b*32+31 (128 gate-rows of Whh_d as f16 MFMA
// A-fragments, 256 VGPR/thread). Wave w covers k-quarter 256w..256w+256.
__global__ __launch_bounds__(256, 1) void dec_persist(
    const float* __restrict__ Whh, const u16* __restrict__ GihS,
    const float* __restrict__ hmid,
    u64* __restrict__ hb, float* __restrict__ hfinal,
    int* __restrict__ ctrl, u64* __restrict__ probe, u32* __restrict__ verdict) {
  const int t = threadIdx.x;
  // hwreg 20 = HW_REG_XCC_ID (gfx940+), offset 0, size 32: imm = 20 | (31<<11) = 63508
  u32 xcd = __builtin_amdgcn_s_getreg(63508) & 7u;
  __shared__ int sslot;
  if (t == 0) {
    int tk = atomicAdd(&ctrl[xcd], 1);
    if (tk == 31) atomicCAS(&ctrl[8], -1, (int)xcd);
    int ch;
    do {
      ch = __hip_atomic_load(&ctrl[8], __ATOMIC_RELAXED, __HIP_MEMORY_SCOPE_AGENT);
    } while (ch < 0);
    sslot = (xcd == (u32)ch && tk < 32) ? tk : -1;
  }
  __syncthreads();
  const int b = sslot;
  if (b < 0) return;

  // ---- probe the sc0/L2 channel (bounded, monotone tags, >= compare) ----
  __shared__ int sok;
  if (t == 0) sok = 1;
  __syncthreads();
  for (int r = 0; r < 8; r++) {
    if (sok) {
      if (t == 0) l2_store(&probe[b], (u64)(0xC0DE0000u + (u32)r));
      if (t < 32) {
        const u64 want = (u64)(0xC0DE0000u + (u32)r);
        bool got = false;
        int lim = (r == 0) ? 30000 : 4000;
        for (int it = 0; it < lim; it++) {
          if (l2_load1(&probe[t]) >= want) { got = true; break; }
        }
        if (!got) sok = 0;
      }
    }
    __syncthreads();
  }
  // ---- unanimous verdict via agent scope (always terminates) ----
  if (t == 0)
    __hip_atomic_store(&verdict[b], sok ? 2u : 1u, __ATOMIC_RELAXED, __HIP_MEMORY_SCOPE_AGENT);
  __shared__ int modef;
  if (t == 0) modef = 2;
  __syncthreads();
  if (t < 32) {
    u32 v;
    do {
      v = __hip_atomic_load(&verdict[t], __ATOMIC_RELAXED, __HIP_MEMORY_SCOPE_AGENT);
    } while (v == 0);
    if (v != 2) atomicMin(&modef, 1);
  }
  __syncthreads();
  const bool fast = (modef == 2);

  const int w = t >> 6, lane = t & 63;
  const int quad = lane >> 4, r16 = lane & 15;

  // A-fragments: tile mt covers local gate-rows mt*16..mt*16+15 (local row = gate*32 + jj)
  half8 afrag[8][8];
#pragma unroll
  for (int mt = 0; mt < 8; mt++) {
    int lr = mt * 16 + r16;
    int q = lr >> 5, jj = lr & 31;
    const float* Wr = Whh + (size_t)(q * 1024 + b * 32 + jj) * 1024 + 256 * w + quad * 8;
#pragma unroll
    for (int ks = 0; ks < 8; ks++) {
      half8 v;
#pragma unroll
      for (int j = 0; j < 8; j++) v[j] = (_Float16)Wr[ks * 32 + j];
      afrag[mt][ks] = v;
    }
  }

  __shared__ __align__(16) u32 hsu[512];        // h as f16 pairs (full vector)
  __shared__ float gpart[2][4][128];            // [buf][wave][local gate-row]
  __shared__ __align__(16) u16 uslab[2][2048];  // [buf][step(16) x 128 gates]

  {  // stage slab 0 (steps 0..15)
    uint4 g0 = *(const uint4*)(GihS + (size_t)b * 8064 * 128 + t * 8);
    *(uint4*)&uslab[0][t * 8] = g0;
  }
  float cst = (t < 32) ? hmid[b * 32 + t] : 0.0f;  // c0 = h0 (fp32 exact)

  int n = 0;
  for (int s = 0; s < 128; s++) {
    for (int wI = 0; wI < 63; wI++, n++) {
      // poll own 2 words (one dwordx4) of h_n
      const u32 tn = (u32)n;
      const u64* p = hb + (size_t)(n & 1) * 512 + 2 * t;
      u64 v0, v1;
      if (fast) {
        for (;;) {
          l2_poll2(p, v0, v1);
          if (((u32)(v0 >> 32) == tn) & ((u32)(v1 >> 32) == tn)) break;
        }
      } else {
        for (;;) {
          v0 = aload(p);
          v1 = aload(p + 1);
          if (((u32)(v0 >> 32) == tn) & ((u32)(v1 >> 32) == tn)) break;
        }
      }
      ((u64*)hsu)[t] = (v0 & 0xFFFFFFFFull) | (v1 << 32);  // h[4t..4t+3]

      // issue next-slab prefetch under the MFMA shadow (once per 16 steps)
      const bool slabload = (n & 15) == 0;
      uint4 gsv;
      if (slabload) {
        int nn = (n + 16 <= 8048) ? n + 16 : 8048;
        gsv = *(const uint4*)(GihS + ((size_t)b * 8064 + nn) * 128 + t * 8);
      }

      // matvec partials: 8 m-tiles x 8 k-steps over this wave's quarter
      f32x4 acc[8];
#pragma unroll
      for (int mt = 0; mt < 8; mt++) acc[mt] = (f32x4){0.f, 0.f, 0.f, 0.f};
      const int kb = 128 * w;
#pragma unroll
      for (int ks = 0; ks < 8; ks++) {
        half8 bfrag = *(const half8*)&hsu[kb + 16 * ks + 4 * quad];
#pragma unroll
        for (int mt = 0; mt < 8; mt++)
          acc[mt] = __builtin_amdgcn_mfma_f32_16x16x32_f16(afrag[mt][ks], bfrag, acc[mt], 0, 0, 0);
      }
      if (r16 == 0) {  // col 0 carriers: rows quad*4+reg of each tile
#pragma unroll
        for (int mt = 0; mt < 8; mt++)
          *(f32x4*)&gpart[n & 1][w][mt * 16 + 4 * quad] = acc[mt];
      }
      __syncthreads();
      // slab write AFTER barrier: prior-step readers of the other buffer are provably done
      if (slabload) *(uint4*)&uslab[((n >> 4) + 1) & 1][t * 8] = gsv;
      if (t < 32) {
        const int pb = n & 1, sb = (n >> 4) & 1, so = (n & 15) * 128;
        float gi = gpart[pb][0][t] + gpart[pb][1][t] + gpart[pb][2][t] + gpart[pb][3][t];
        float gf = gpart[pb][0][32 + t] + gpart[pb][1][32 + t] + gpart[pb][2][32 + t] + gpart[pb][3][32 + t];
        float gg = gpart[pb][0][64 + t] + gpart[pb][1][64 + t] + gpart[pb][2][64 + t] + gpart[pb][3][64 + t];
        float go = gpart[pb][0][96 + t] + gpart[pb][1][96 + t] + gpart[pb][2][96 + t] + gpart[pb][3][96 + t];
        gi += b2f(uslab[sb][so + t]);
        gf += b2f(uslab[sb][so + 32 + t]);
        gg += b2f(uslab[sb][so + 64 + t]);
        go += b2f(uslab[sb][so + 96 + t]);
        float iv = fsig(gi), fv = fsig(gf), gv = ftanh_(gg), ov = fsig(go);
        cst = fv * cst + iv * gv;
        float h = ov * ftanh_(cst);
        u32 h16 = (u32)f2h(h);
        u32 oth = (u32)__shfl_down((int)h16, 1);
        if ((t & 1) == 0) {
          u64 word = ((u64)(u32)(n + 1) << 32) | (h16 | (oth << 16));
          u64* dst = &hb[(size_t)((n + 1) & 1) * 512 + b * 16 + (t >> 1)];
          if (fast) l2_store(dst, word);
          else __hip_atomic_store(dst, word, __ATOMIC_RELAXED, __HIP_MEMORY_SCOPE_AGENT);
        }
        if (wI == 62) hfinal[(size_t)s * 1024 + b * 32 + t] = h;
      }
    }
  }
}

// ---------------- row-wise log_softmax ----------------
__global__ __launch_bounds__(256) void k_lsm(const float* __restrict__ logits, float* __restrict__ out) {
  int s = blockIdx.x, t = threadIdx.x;
  const float* L = logits + (size_t)s * 1024;
  __shared__ float red[4], red2[4];
  float m = -1e30f;
  for (int i = t; i < 1024; i += 256) m = fmaxf(m, L[i]);
  for (int o = 1; o < 64; o <<= 1) m = fmaxf(m, __shfl_xor(m, o));
  if ((t & 63) == 0) red[t >> 6] = m;
  __syncthreads();
  m = fmaxf(fmaxf(red[0], red[1]), fmaxf(red[2], red[3]));
  float sum = 0.f;
  for (int i = t; i < 1024; i += 256) sum += expf(L[i] - m);
  for (int o = 1; o < 64; o <<= 1) sum += __shfl_xor(sum, o);
  if ((t & 63) == 0) red2[t >> 6] = sum;
  __syncthreads();
  sum = red2[0] + red2[1] + red2[2] + red2[3];
  float lse = m + logf(sum);
  for (int i = t; i < 1024; i += 256) out[(size_t)s * 1024 + i] = L[i] - lse;
}

extern "C" void kernel_launch(void* const* d_in, const int* in_sizes, int n_in,
                              void* d_out, int out_size, void* d_ws, size_t ws_size,
                              hipStream_t stream) {
  const float* x     = (const float*)d_in[0];
  const float* Wih_e = (const float*)d_in[1];
  const float* Whh_e = (const float*)d_in[2];
  const float* b_e   = (const float*)d_in[3];
  const float* Wm1   = (const float*)d_in[4];
  const float* bm1   = (const float*)d_in[5];
  const float* Wm2   = (const float*)d_in[6];
  const float* bm2   = (const float*)d_in[7];
  const float* Wih_d = (const float*)d_in[8];
  const float* Whh_d = (const float*)d_in[9];
  const float* b_d   = (const float*)d_in[10];
  const float* Wo    = (const float*)d_in[11];
  const float* bo    = (const float*)d_in[12];
  float* out = (float*)d_out;

  char* w = (char*)d_ws;
  size_t off = 0;
  auto alloc = [&](size_t bytes) { size_t r = off; off += (bytes + 255) & ~(size_t)255; return r; };
  u16* Chi = (u16*)(w + alloc((size_t)1024 * 1024 * 2));
  u16* Clo = (u16*)(w + alloc((size_t)1024 * 1024 * 2));
  u16* F1  = (u16*)(w + alloc((size_t)8064 * 1024 * 2));
  char* f2slot = w + alloc((size_t)8064 * 1024 * 2);   // Win_hi, later F2
  u16* WinHi = (u16*)f2slot;
  u16* F2    = (u16*)f2slot;
  u16* WinLo = (u16*)(w + alloc((size_t)8064 * 1024 * 2));
  char* gislot = w + alloc((size_t)8064 * 4096 * 2);   // Fgem (fp32 33MB), later GihS (bf16 66MB, slab)
  float* Fgem = (float*)gislot;
  u16* GihS   = (u16*)gislot;
  u16* Gihe = (u16*)(w + alloc((size_t)8064 * 4096 * 2));  // encoder input projections (bf16)
  u16* Wihd  = (u16*)(w + alloc((size_t)4096 * 1024 * 2));
  u16* Wihe  = (u16*)(w + alloc((size_t)4096 * 1024 * 2));
  u16* Whhe  = (u16*)(w + alloc((size_t)4096 * 1024 * 2));
  u16* Wm1b = (u16*)(w + alloc((size_t)1024 * 1024 * 2));
  u16* Wm2b = (u16*)(w + alloc((size_t)1024 * 1024 * 2));
  u16* Wob  = (u16*)(w + alloc((size_t)1024 * 1024 * 2));
  u16* At   = (u16*)(w + alloc((size_t)128 * 1024 * 2));
  float* Ge = (float*)(w + alloc((size_t)128 * 4096 * 4));
  float* Ce = (float*)(w + alloc((size_t)128 * 1024 * 4));
  u16* Mid1 = (u16*)(w + alloc((size_t)128 * 1024 * 2));
  float* Hmid = (float*)(w + alloc((size_t)128 * 1024 * 4));
  u64* Hb = (u64*)(w + alloc((size_t)1024 * 8));
  int* Ctrl = (int*)(w + alloc(256));
  u64* Probe = (u64*)(w + alloc(256));
  u32* Verdict = (u32*)(w + alloc(256));
  float* Hfin = (float*)(w + alloc((size_t)128 * 1024 * 4));
  u16* Hfinb  = (u16*)(w + alloc((size_t)128 * 1024 * 2));
  float* Logit = (float*)(w + alloc((size_t)128 * 1024 * 4));
  (void)ws_size; (void)in_sizes; (void)n_in; (void)out_size;

  hipMemsetAsync(At, 0, (size_t)128 * 1024 * 2, stream);   // h=0 for encoder step 0
  hipMemsetAsync(Ce, 0, (size_t)128 * 1024 * 4, stream);

  // Fourier features: F = windows @ C, hi/lo split for ~fp32 accuracy
  k_cos<<<4096, 256, 0, stream>>>(Chi, Clo);
  k_win<<<8064, 256, 0, stream>>>(x, WinHi, WinLo);
  gemm_bt<0, false, false><<<dim3(16, 126), 256, 0, stream>>>(WinHi, 1024, Chi, 1024, Fgem, 1024, nullptr, 8064, 1024, 1024);
  gemm_bt<0, false, true><<<dim3(16, 126), 256, 0, stream>>>(WinHi, 1024, Clo, 1024, Fgem, 1024, nullptr, 8064, 1024, 1024);
  gemm_bt<0, false, true><<<dim3(16, 126), 256, 0, stream>>>(WinLo, 1024, Chi, 1024, Fgem, 1024, nullptr, 8064, 1024, 1024);
  k_f2bk<<<8064, 256, 0, stream>>>(Fgem, F1);        // F1 bf16, (w,s) order
  k_perm<<<4032, 256, 0, stream>>>(F1, F2);          // F2 bf16, (s,w) order

  // weight conversions
  k_f2bk<<<4096, 256, 0, stream>>>(Wih_d, Wihd);
  k_f2bk<<<4096, 256, 0, stream>>>(Wih_e, Wihe);
  k_f2bk<<<4096, 256, 0, stream>>>(Whh_e, Whhe);
  k_f2bk<<<1024, 256, 0, stream>>>(Wm1, Wm1b);
  k_f2bk<<<1024, 256, 0, stream>>>(Wm2, Wm2b);
  k_f2bk<<<1024, 256, 0, stream>>>(Wo, Wob);

  // batched input projections: decoder (slab layout) + encoder
  gemm_bt<0, true, false, true><<<dim3(64, 126), 256, 0, stream>>>(F2, 1024, Wihd, 1024, GihS, 128, b_d, 8064, 4096, 1024);
  gemm_bt<0, true, false><<<dim3(64, 126), 256, 0, stream>>>(F1, 1024, Wihe, 1024, Gihe, 4096, b_e, 8064, 4096, 1024);

  // encoder: 63 steps of gates = h @ Whh_e^T (+Gihe in cell), then cell
  for (int t = 0; t < 63; t++) {
    gemm_bt<0, false, false><<<dim3(64, 2), 256, 0, stream>>>(At, 1024, Whhe, 1024, Ge, 4096, nullptr, 128, 4096, 1024);
    k_cell_enc<<<512, 256, 0, stream>>>(Ge, Gihe, t, Ce, At);
  }

  // mid MLP: tanh(relu(h_enc @ Wm1^T + bm1) @ Wm2^T + bm2)
  gemm_bt<1, true, false><<<dim3(16, 2), 256, 0, stream>>>(At, 1024, Wm1b, 1024, Mid1, 1024, bm1, 128, 1024, 1024);
  gemm_bt<2, false, false><<<dim3(16, 2), 256, 0, stream>>>(Mid1, 1024, Wm2b, 1024, Hmid, 1024, bm2, 128, 1024, 1024);

  // decoder: election + probe/verdict + single-XCD (or verified fallback) persistent loop
  k_initdec<<<4, 256, 0, stream>>>(Hmid, Hb, Ctrl, Probe, Verdict);
  dec_persist<<<256, 256, 0, stream>>>(Whh_d, GihS, Hmid, Hb, Hfin, Ctrl, Probe, Verdict);

  // output head: log_softmax(h_final @ Wo^T + bo)
  k_f2bk<<<128, 256, 0, stream>>>(Hfin, Hfinb);
  gemm_bt<0, false, false><<<dim3(16, 2), 256, 0, stream>>>(Hfinb, 1024, Wob, 1024, Logit, 1024, bo, 128, 1024, 1024);
  k_lsm<<<128, 256, 0, stream>>>(Logit, out);
}